// Round 15
// baseline (7633.416 us; speedup 1.0000x reference)
//
#include <hip/hip_runtime.h>
#include <cstdint>
#include <cstddef>

#define T_ 512
#define B_ 32
#define D_ 1024
#define L_ 4
#define BD_ (B_*D_)
#define TPB 256
#define NWG 256
#define EPSF 1e-5f

typedef _Float16 f16x8 __attribute__((ext_vector_type(8)));
typedef float f32x4 __attribute__((ext_vector_type(4)));
typedef float f32x2 __attribute__((ext_vector_type(2)));
typedef unsigned int u32x4 __attribute__((ext_vector_type(4)));
typedef unsigned long long u64;

// workspace layout (bytes)
#define WSO_PROG   0          // 4 layer progress counters, 256B apart (memset 4096)
#define WSO_WT     1048576    // fp16 weights, 32MB
#define WSO_H16    34603008   // [4][513][32][1024] fp16 state/h streams

// LDS layout (bytes)
#define LDS_W     0
#define LDS_DUMP  131072
#define LDS_GB    147456
#define LDS_NS    155904
#define LDS_BIAS  158464
#define LDS_SGSB  158592
#define LDS_RED   158720      // h-stat partials [4][16] f32x4 (1KB) + state-stat partials (1KB)
#define LDS_TOTAL 160768
#define NSTR 20

__device__ __forceinline__ unsigned pk2h(float a, float b){
  _Float16 ha=(_Float16)a, hb=(_Float16)b;
  return (unsigned)__builtin_bit_cast(unsigned short,ha) |
         ((unsigned)__builtin_bit_cast(unsigned short,hb)<<16);
}
__device__ __forceinline__ unsigned cldu(const unsigned* p){
  return __hip_atomic_load(p,__ATOMIC_RELAXED,__HIP_MEMORY_SCOPE_AGENT);
}
__device__ __forceinline__ void cstore16(unsigned short* p, unsigned w0, unsigned w1, unsigned w2, unsigned w3){
  u64 lo=((u64)w1<<32)|w0, hi=((u64)w3<<32)|w2;
  __hip_atomic_store((u64*)(void*)p,     lo, __ATOMIC_RELAXED, __HIP_MEMORY_SCOPE_AGENT);
  __hip_atomic_store((u64*)(void*)(p+4), hi, __ATOMIC_RELAXED, __HIP_MEMORY_SCOPE_AGENT);
}

#define GLDX(d,vo,sb)  asm volatile("global_load_dwordx4 %0, %1, %2" : "=v"(d) : "v"(vo), "s"(sb) : "memory")
#define WAITV(N) do{ asm volatile("s_waitcnt vmcnt(" #N ")" ::: "memory"); __builtin_amdgcn_sched_barrier(0); }while(0)
#define BARS do{ asm volatile("s_waitcnt lgkmcnt(0)" ::: "memory"); __builtin_amdgcn_s_barrier(); }while(0)
#define WAITL do{ asm volatile("s_waitcnt lgkmcnt(0)" ::: "memory"); __builtin_amdgcn_sched_barrier(0); }while(0)

// per-wave poll: all lanes spin on the counter (uniform address, one transaction per poll)
#define WPOLL(ctr,tgt) do{ while (cldu(ctr) < (tgt)) __builtin_amdgcn_s_sleep(1); \
                           __builtin_amdgcn_sched_barrier(0); }while(0)

#define MM(cc) do{ \
    const int kb_=(((cc)*128+kq))*2; \
    f16x8 bF=*(const f16x8*)(WF + (kb_^swl)); \
    f16x8 bC=*(const f16x8*)(WC + (kb_^swl)); \
    accF0=__builtin_amdgcn_mfma_f32_16x16x32_f16(a0,bF,accF0,0,0,0); \
    accF1=__builtin_amdgcn_mfma_f32_16x16x32_f16(a1,bF,accF1,0,0,0); \
    accC0=__builtin_amdgcn_mfma_f32_16x16x32_f16(a0,bC,accC0,0,0,0); \
    accC1=__builtin_amdgcn_mfma_f32_16x16x32_f16(a1,bC,accC1,0,0,0); \
  }while(0)

#define PSI(i,NW) do{ WAITV(NW); \
    f16x8 a0=__builtin_bit_cast(f16x8,pS[2*(i)]); \
    f16x8 a1=__builtin_bit_cast(f16x8,pS[2*(i)+1]); \
    MM(8+(i)); }while(0)

#define PHN(c) do{ \
    f16x8 a0=__builtin_bit_cast(f16x8,pH[2*(c)]); \
    f16x8 a1=__builtin_bit_cast(f16x8,pH[2*(c)+1]); \
    const int kf_=(c)*128+kq; \
    f16x8 g8=*(const f16x8*)(GBg16+(kf_>>1)); \
    f16x8 b8=*(const f16x8*)(GBg16+512+(kf_>>1)); \
    a0=a0*rsA8+nmA8; a0=a0*g8+b8; \
    a1=a1*rsB8+nmB8; a1=a1*g8+b8; \
    MM(c); }while(0)

#define PHX(c) do{ \
    f32x4 xa0=__builtin_bit_cast(f32x4,pX[4*(c)]),   xa1=__builtin_bit_cast(f32x4,pX[4*(c)+1]); \
    f32x4 xb0=__builtin_bit_cast(f32x4,pX[4*(c)+2]), xb1=__builtin_bit_cast(f32x4,pX[4*(c)+3]); \
    const int kf_=(c)*128+kq; \
    f32x4 g0=*(const f32x4*)(GBg32+kf_), g1=*(const f32x4*)(GBg32+kf_+4); \
    f32x4 q0=*(const f32x4*)(GBg32+1024+kf_), q1=*(const f32x4*)(GBg32+1024+kf_+4); \
    f16x8 a0,a1; \
    a0[0]=(_Float16)((xa0[0]*rsA+nmA)*g0[0]+q0[0]); a0[1]=(_Float16)((xa0[1]*rsA+nmA)*g0[1]+q0[1]); \
    a0[2]=(_Float16)((xa0[2]*rsA+nmA)*g0[2]+q0[2]); a0[3]=(_Float16)((xa0[3]*rsA+nmA)*g0[3]+q0[3]); \
    a0[4]=(_Float16)((xa1[0]*rsA+nmA)*g1[0]+q1[0]); a0[5]=(_Float16)((xa1[1]*rsA+nmA)*g1[1]+q1[1]); \
    a0[6]=(_Float16)((xa1[2]*rsA+nmA)*g1[2]+q1[2]); a0[7]=(_Float16)((xa1[3]*rsA+nmA)*g1[3]+q1[3]); \
    a1[0]=(_Float16)((xb0[0]*rsB+nmB)*g0[0]+q0[0]); a1[1]=(_Float16)((xb0[1]*rsB+nmB)*g0[1]+q0[1]); \
    a1[2]=(_Float16)((xb0[2]*rsB+nmB)*g0[2]+q0[2]); a1[3]=(_Float16)((xb0[3]*rsB+nmB)*g0[3]+q0[3]); \
    a1[4]=(_Float16)((xb1[0]*rsB+nmB)*g1[0]+q1[0]); a1[5]=(_Float16)((xb1[1]*rsB+nmB)*g1[1]+q1[1]); \
    a1[6]=(_Float16)((xb1[2]*rsB+nmB)*g1[2]+q1[2]); a1[7]=(_Float16)((xb1[3]*rsB+nmB)*g1[3]+q1[3]); \
    MM(c); }while(0)

// ---------------- pre-pass 1: weights -> fp16 transposed fused layout ----------------
extern "C" __global__ void __launch_bounds__(256,1) crs_prepass(
    const float* __restrict__ Wf, const float* __restrict__ Uf,
    const float* __restrict__ Wc, const float* __restrict__ Uc,
    unsigned short* __restrict__ WT)
{
  int bid = blockIdx.x;
  int kt  = bid & 15;
  int ct  = (bid>>4) & 31;
  int sel = (bid>>9) & 3;
  int i   = bid >> 11;
  int tid = threadIdx.x;
  int kq  = tid >> 5;
  int cc  = tid & 31;
  const float* sp;
  if      (sel==0) sp = Wf;
  else if (sel==1) sp = Uf;
  else if (sel==2) sp = Wc;
  else             sp = Uc;
  sp += (size_t)i * 1048576;
  int cl = ct*32 + cc;
  int k0 = kt*64 + kq*8;
  float f[8];
  #pragma unroll
  for (int e=0;e<8;++e){ f[e] = sp[(size_t)(k0+e)*1024 + cl]; }
  int cg = ((sel>>1) ? 1024 : 0) + cl;
  int ks = sel & 1;
  size_t idx = ((size_t)(i*2048 + cg)*2 + ks)*1024 + k0;
  uint4 pk;
  pk.x = pk2h(f[0], f[1]);
  pk.y = pk2h(f[2], f[3]);
  pk.z = pk2h(f[4], f[5]);
  pk.w = pk2h(f[6], f[7]);
  *(uint4*)(WT + idx) = pk;
}

// ---------------- pre-pass 2: initial state -> H16 slot 0 ----------------
extern "C" __global__ void __launch_bounds__(256,1) crs_prep2(
    const float* __restrict__ st0, unsigned short* __restrict__ H16)
{
  int i2=blockIdx.x, tid=threadIdx.x;
  int rr=tid>>3, ss=tid&7;
  const float4* p4=(const float4*)(st0+(size_t)i2*BD_+rr*1024+ss*128);
  uint4* dst=(uint4*)(H16+(size_t)i2*513*32768+rr*1024+ss*128);
  #pragma unroll
  for (int q=0;q<16;++q){
    float4 a=p4[2*q], b=p4[2*q+1];
    uint4 pk; pk.x=pk2h(a.x,a.y); pk.y=pk2h(a.z,a.w); pk.z=pk2h(b.x,b.y); pk.w=pk2h(b.z,b.w);
    dst[q]=pk;
  }
}

// ---------------- main persistent kernel ----------------
extern "C" __global__ void __launch_bounds__(TPB,1) crs_main(
    const float* __restrict__ x, const float* __restrict__ st0,
    const float* __restrict__ bfv, const float* __restrict__ bcv,
    const float* __restrict__ pg, const float* __restrict__ pb,
    const float* __restrict__ sg, const float* __restrict__ sbv,
    float* __restrict__ y, float* __restrict__ ostate,
    const unsigned short* __restrict__ WT, char* __restrict__ ws)
{
  extern __shared__ char smem[];
  const int tid=threadIdx.x, w=blockIdx.x;
  const int li=w>>6, wr=w&63;
  const int lane=tid&63, v=tid>>6;
  const int l15=lane&15, lg=(lane>>4)&3;
  const int kq = v*32 + lg*8;
  const int col=lane&15, rp=lane>>4;
  const int r0=v*8+rp, r1=v*8+4+rp;
  const int sseg=tid&7;

  unsigned* prog=(unsigned*)(ws+WSO_PROG);
  unsigned short* H16=(unsigned short*)(ws+WSO_H16);
  float* NSf=(float*)(smem+LDS_NS);
  float* BIAS=(float*)(smem+LDS_BIAS);
  float* SGSB=(float*)(smem+LDS_SGSB);
  char* RED0=smem+LDS_RED;
  char* RED1=smem+LDS_RED+1024;

  // one-time init: weights -> LDS
  {
    int lc=tid>>3;
    int cgl=(lc>>4)*1024 + wr*16 + (lc&15);
    const unsigned short* src=WT + ((size_t)li*2048+cgl)*2048;
    char* dcol = smem + LDS_W + lc*4096;
    int sw2=(lc&7)<<4;
    #pragma unroll
    for (int n=0;n<32;++n){
      int q=sseg+n*8;
      uint4 d=*(const uint4*)(src+q*8);
      *(uint4*)(dcol + ((q*16)^sw2)) = d;
    }
  }
  if (li==0){
    float* g32=(float*)(smem+LDS_GB);
    for (int k=tid;k<1024;k+=TPB){ g32[k]=pg[k]; g32[1024+k]=pb[k]; }
  } else {
    unsigned* g16=(unsigned*)(smem+LDS_GB);
    for (int k=tid;k<512;k+=TPB){
      g16[k]    =pk2h(pg[li*1024+2*k], pg[li*1024+2*k+1]);
      g16[512+k]=pk2h(pb[li*1024+2*k], pb[li*1024+2*k+1]);
    }
  }
  if (tid<16) BIAS[tid]=bfv[li*1024+wr*16+tid];
  else if (tid<32) BIAS[tid]=bcv[li*1024+wr*16+(tid-16)];
  if (li==3){
    if (tid<16) SGSB[tid]=sg[wr*16+tid];
    else if (tid<32) SGSB[tid]=sbv[wr*16+(tid-16)];
  }
  f32x2 sreg, pns={0.f,0.f};
  sreg.x = st0[(size_t)li*BD_ + (size_t)r0*D_ + wr*16+col];
  sreg.y = st0[(size_t)li*BD_ + (size_t)r1*D_ + wr*16+col];
  __syncthreads();

  const char* WF = smem + LDS_W + l15*4096;
  const char* WC = smem + LDS_W + (16+l15)*4096;
  const int swl = (l15&7)<<4;
  const unsigned* GBg16 = (const unsigned*)(smem+LDS_GB);
  const float* GBg32 = (const float*)(smem+LDS_GB);
  const int voA = l15*2048 + kq*2, voB = voA + 32768;
  const int vxA = l15*4096 + kq*4, vxB = vxA + 65536;

  for (int t=0; t<T_; ++t){
    // ---- poll 1 (per-wave, all lanes): own-layer state(t) ready
    WPOLL(prog+li*64, 64u*(unsigned)t);

    u64 sbS = (u64)(uintptr_t)(H16 + ((size_t)li*513 + (size_t)t)*32768);
    f32x4 accF0={0,0,0,0}, accF1={0,0,0,0}, accC0={0,0,0,0}, accC1={0,0,0,0};

    if (li==0){
      u64 sbH = (u64)(uintptr_t)(x + (size_t)t*BD_);
      u32x4 pS[16]; u32x4 pX[32];
      GLDX(pS[0],  voA+0*256, sbS); GLDX(pS[1],  voB+0*256, sbS);
      GLDX(pS[2],  voA+1*256, sbS); GLDX(pS[3],  voB+1*256, sbS);
      GLDX(pS[4],  voA+2*256, sbS); GLDX(pS[5],  voB+2*256, sbS);
      GLDX(pS[6],  voA+3*256, sbS); GLDX(pS[7],  voB+3*256, sbS);
      GLDX(pS[8],  voA+4*256, sbS); GLDX(pS[9],  voB+4*256, sbS);
      GLDX(pS[10], voA+5*256, sbS); GLDX(pS[11], voB+5*256, sbS);
      GLDX(pS[12], voA+6*256, sbS); GLDX(pS[13], voB+6*256, sbS);
      GLDX(pS[14], voA+7*256, sbS); GLDX(pS[15], voB+7*256, sbS);
      GLDX(pX[0],  vxA+0*512, sbH); GLDX(pX[1],  vxA+0*512+16, sbH); GLDX(pX[2],  vxB+0*512, sbH); GLDX(pX[3],  vxB+0*512+16, sbH);
      GLDX(pX[4],  vxA+1*512, sbH); GLDX(pX[5],  vxA+1*512+16, sbH); GLDX(pX[6],  vxB+1*512, sbH); GLDX(pX[7],  vxB+1*512+16, sbH);
      GLDX(pX[8],  vxA+2*512, sbH); GLDX(pX[9],  vxA+2*512+16, sbH); GLDX(pX[10], vxB+2*512, sbH); GLDX(pX[11], vxB+2*512+16, sbH);
      GLDX(pX[12], vxA+3*512, sbH); GLDX(pX[13], vxA+3*512+16, sbH); GLDX(pX[14], vxB+3*512, sbH); GLDX(pX[15], vxB+3*512+16, sbH);
      GLDX(pX[16], vxA+4*512, sbH); GLDX(pX[17], vxA+4*512+16, sbH); GLDX(pX[18], vxB+4*512, sbH); GLDX(pX[19], vxB+4*512+16, sbH);
      GLDX(pX[20], vxA+5*512, sbH); GLDX(pX[21], vxA+5*512+16, sbH); GLDX(pX[22], vxB+5*512, sbH); GLDX(pX[23], vxB+5*512+16, sbH);
      GLDX(pX[24], vxA+6*512, sbH); GLDX(pX[25], vxA+6*512+16, sbH); GLDX(pX[26], vxB+6*512, sbH); GLDX(pX[27], vxB+6*512+16, sbH);
      GLDX(pX[28], vxA+7*512, sbH); GLDX(pX[29], vxA+7*512+16, sbH); GLDX(pX[30], vxB+7*512, sbH); GLDX(pX[31], vxB+7*512+16, sbH);
      PSI(0,46); PSI(1,44); PSI(2,42); PSI(3,40); PSI(4,38); PSI(5,36); PSI(6,34); PSI(7,32);
      WAITV(0);
      float sA=0.f,qA=0.f,sB=0.f,qB=0.f;
      #pragma unroll
      for (int c2=0;c2<8;++c2){
        f32x4 u0=__builtin_bit_cast(f32x4,pX[4*c2]),   u1=__builtin_bit_cast(f32x4,pX[4*c2+1]);
        f32x4 w0=__builtin_bit_cast(f32x4,pX[4*c2+2]), w1=__builtin_bit_cast(f32x4,pX[4*c2+3]);
        #pragma unroll
        for (int j=0;j<4;++j){
          sA+=u0[j]; qA+=u0[j]*u0[j]; sA+=u1[j]; qA+=u1[j]*u1[j];
          sB+=w0[j]; qB+=w0[j]*w0[j]; sB+=w1[j]; qB+=w1[j]*w1[j];
        }
      }
      sA+=__shfl_xor(sA,16); qA+=__shfl_xor(qA,16); sB+=__shfl_xor(sB,16); qB+=__shfl_xor(qB,16);
      sA+=__shfl_xor(sA,32); qA+=__shfl_xor(qA,32); sB+=__shfl_xor(sB,32); qB+=__shfl_xor(qB,32);
      if (lane<16){ f32x4 pk={sA,qA,sB,qB}; *(f32x4*)(RED0+((v*16+lane)<<4))=pk; }
      BARS;
      f32x4 hp={0.f,0.f,0.f,0.f};
      #pragma unroll
      for (int vv=0;vv<4;++vv) hp += *(const f32x4*)(RED0+((vv*16+l15)<<4));
      float mA=hp.x*(1.f/1024.f);
      float rsA=rsqrtf(hp.y*(1.f/1024.f)-mA*mA+EPSF), nmA=-mA*rsA;
      float mB=hp.z*(1.f/1024.f);
      float rsB=rsqrtf(hp.w*(1.f/1024.f)-mB*mB+EPSF), nmB=-mB*rsB;
      PHX(0); PHX(1); PHX(2); PHX(3); PHX(4); PHX(5); PHX(6); PHX(7);
    } else {
      u64 sbH = (u64)(uintptr_t)(H16 + ((size_t)(li-1)*513 + (size_t)(t+1))*32768);
      u32x4 pS[16]; u32x4 pH[16];
      GLDX(pS[0],  voA+0*256, sbS); GLDX(pS[1],  voB+0*256, sbS);
      GLDX(pS[2],  voA+1*256, sbS); GLDX(pS[3],  voB+1*256, sbS);
      GLDX(pS[4],  voA+2*256, sbS); GLDX(pS[5],  voB+2*256, sbS);
      GLDX(pS[6],  voA+3*256, sbS); GLDX(pS[7],  voB+3*256, sbS);
      GLDX(pS[8],  voA+4*256, sbS); GLDX(pS[9],  voB+4*256, sbS);
      GLDX(pS[10], voA+5*256, sbS); GLDX(pS[11], voB+5*256, sbS);
      GLDX(pS[12], voA+6*256, sbS); GLDX(pS[13], voB+6*256, sbS);
      GLDX(pS[14], voA+7*256, sbS); GLDX(pS[15], voB+7*256, sbS);
      // poll 2 (per-wave, all lanes): upstream h(t) ready — state loads stay in flight
      WPOLL(prog+(li-1)*64, 64u*(unsigned)(t+1));
      GLDX(pH[0],  voA+0*256, sbH); GLDX(pH[1],  voB+0*256, sbH);
      GLDX(pH[2],  voA+1*256, sbH); GLDX(pH[3],  voB+1*256, sbH);
      GLDX(pH[4],  voA+2*256, sbH); GLDX(pH[5],  voB+2*256, sbH);
      GLDX(pH[6],  voA+3*256, sbH); GLDX(pH[7],  voB+3*256, sbH);
      GLDX(pH[8],  voA+4*256, sbH); GLDX(pH[9],  voB+4*256, sbH);
      GLDX(pH[10], voA+5*256, sbH); GLDX(pH[11], voB+5*256, sbH);
      GLDX(pH[12], voA+6*256, sbH); GLDX(pH[13], voB+6*256, sbH);
      GLDX(pH[14], voA+7*256, sbH); GLDX(pH[15], voB+7*256, sbH);
      PSI(0,30); PSI(1,28); PSI(2,26); PSI(3,24); PSI(4,22); PSI(5,20); PSI(6,18); PSI(7,16);
      WAITV(0);
      float sA=0.f,qA=0.f,sB=0.f,qB=0.f;
      #pragma unroll
      for (int c2=0;c2<8;++c2){
        f16x8 hA=__builtin_bit_cast(f16x8,pH[2*c2]);
        f16x8 hB=__builtin_bit_cast(f16x8,pH[2*c2+1]);
        #pragma unroll
        for (int j=0;j<8;++j){
          float fa=(float)hA[j], fb=(float)hB[j];
          sA+=fa; qA+=fa*fa; sB+=fb; qB+=fb*fb;
        }
      }
      sA+=__shfl_xor(sA,16); qA+=__shfl_xor(qA,16); sB+=__shfl_xor(sB,16); qB+=__shfl_xor(qB,16);
      sA+=__shfl_xor(sA,32); qA+=__shfl_xor(qA,32); sB+=__shfl_xor(sB,32); qB+=__shfl_xor(qB,32);
      if (lane<16){ f32x4 pk={sA,qA,sB,qB}; *(f32x4*)(RED0+((v*16+lane)<<4))=pk; }
      if (li==3){
        float sS=0.f,qS=0.f,sT=0.f,qT=0.f;
        #pragma unroll
        for (int c2=0;c2<8;++c2){
          f16x8 tA=__builtin_bit_cast(f16x8,pS[2*c2]);
          f16x8 tB=__builtin_bit_cast(f16x8,pS[2*c2+1]);
          #pragma unroll
          for (int j=0;j<8;++j){
            float fa=(float)tA[j], fb=(float)tB[j];
            sS+=fa; qS+=fa*fa; sT+=fb; qT+=fb*fb;
          }
        }
        sS+=__shfl_xor(sS,16); qS+=__shfl_xor(qS,16); sT+=__shfl_xor(sT,16); qT+=__shfl_xor(qT,16);
        sS+=__shfl_xor(sS,32); qS+=__shfl_xor(qS,32); sT+=__shfl_xor(sT,32); qT+=__shfl_xor(qT,32);
        if (lane<16){ f32x4 pk={sS,qS,sT,qT}; *(f32x4*)(RED1+((v*16+lane)<<4))=pk; }
      }
      BARS;
      f32x4 hp={0.f,0.f,0.f,0.f};
      #pragma unroll
      for (int vv=0;vv<4;++vv) hp += *(const f32x4*)(RED0+((vv*16+l15)<<4));
      float mAf=hp.x*(1.f/1024.f);
      float rsAf=rsqrtf(hp.y*(1.f/1024.f)-mAf*mAf+EPSF), nmAf=-mAf*rsAf;
      float mBf=hp.z*(1.f/1024.f);
      float rsBf=rsqrtf(hp.w*(1.f/1024.f)-mBf*mBf+EPSF), nmBf=-mBf*rsBf;
      const _Float16 hrA=(_Float16)rsAf, hmA=(_Float16)nmAf, hrB=(_Float16)rsBf, hmB=(_Float16)nmBf;
      const f16x8 rsA8={hrA,hrA,hrA,hrA,hrA,hrA,hrA,hrA};
      const f16x8 nmA8={hmA,hmA,hmA,hmA,hmA,hmA,hmA,hmA};
      const f16x8 rsB8={hrB,hrB,hrB,hrB,hrB,hrB,hrB,hrB};
      const f16x8 nmB8={hmB,hmB,hmB,hmB,hmB,hmB,hmB,hmB};
      if (li==3 && t>=1){
        f32x4 sp0={0.f,0.f,0.f,0.f}, sp1={0.f,0.f,0.f,0.f};
        #pragma unroll
        for (int vv=0;vv<4;++vv){
          sp0 += *(const f32x4*)(RED1+((vv*16+(r0&15))<<4));
          sp1 += *(const f32x4*)(RED1+((vv*16+(r1&15))<<4));
        }
        float gv=SGSB[col], bv=SGSB[16+col];
        float s0=(r0<16)? sp0.x : sp0.z, q0=(r0<16)? sp0.y : sp0.w;
        float m0=s0*(1.f/1024.f);
        float rs0=rsqrtf(q0*(1.f/1024.f)-m0*m0+EPSF);
        y[(size_t)(t-1)*BD_+(size_t)r0*D_+wr*16+col]=(pns.x-m0)*rs0*gv+bv;
        float s1v=(r1<16)? sp1.x : sp1.z, q1v=(r1<16)? sp1.y : sp1.w;
        float m1=s1v*(1.f/1024.f);
        float rs1=rsqrtf(q1v*(1.f/1024.f)-m1*m1+EPSF);
        y[(size_t)(t-1)*BD_+(size_t)r1*D_+wr*16+col]=(pns.y-m1)*rs1*gv+bv;
      }
      PHN(0); PHN(1); PHN(2); PHN(3); PHN(4); PHN(5); PHN(6); PHN(7);
    }

    *(f32x4*)(smem+LDS_DUMP + (((v*4+0)*64+lane)<<4)) = accF0;
    *(f32x4*)(smem+LDS_DUMP + (((v*4+1)*64+lane)<<4)) = accF1;
    *(f32x4*)(smem+LDS_DUMP + (((v*4+2)*64+lane)<<4)) = accC0;
    *(f32x4*)(smem+LDS_DUMP + (((v*4+3)*64+lane)<<4)) = accC1;
    BARS;

    {
      const int rtl = v>>1;
      const int lg20 = (v&1)*2, lg21 = (v&1)*2+1;
      float fF0=0.f,fF1=0.f,fC0=0.f,fC1=0.f;
      #pragma unroll
      for (int v2=0;v2<4;++v2){
        const char* db = smem+LDS_DUMP + v2*4096;
        fF0 += *(const float*)(db + (((0+rtl)*64 + lg20*16+col)<<4) + rp*4);
        fF1 += *(const float*)(db + (((0+rtl)*64 + lg21*16+col)<<4) + rp*4);
        fC0 += *(const float*)(db + (((2+rtl)*64 + lg20*16+col)<<4) + rp*4);
        fC1 += *(const float*)(db + (((2+rtl)*64 + lg21*16+col)<<4) + rp*4);
      }
      float bfc=BIAS[col], bcc=BIAS[16+col];
      float preF0=fminf(fmaxf(fF0+bfc,-30.f),30.f);
      float preC0=fminf(fmaxf(fC0+bcc,-30.f),30.f);
      float preF1=fminf(fmaxf(fF1+bfc,-30.f),30.f);
      float preC1=fminf(fmaxf(fC1+bcc,-30.f),30.f);
      float fg0=1.f/(1.f+__expf(-preF0)), e0=__expf(-2.f*preC0);
      float cd0=(1.f-e0)/(1.f+e0);
      float fg1=1.f/(1.f+__expf(-preF1)), e1=__expf(-2.f*preC1);
      float cd1=(1.f-e1)/(1.f+e1);
      float ns0=fg0*sreg.x+(1.f-fg0)*cd0;
      float ns1=fg1*sreg.y+(1.f-fg1)*cd1;
      sreg.x=ns0; sreg.y=ns1;
      if (li==3){ pns.x=ns0; pns.y=ns1; }
      NSf[r0*NSTR+col]=ns0;
      NSf[r1*NSTR+col]=ns1;
    }
    WAITL;   // same-wave NSf rows: ds-order within wave suffices, no barrier

    if (lane<16){
      int row = v*8 + (lane>>1), hf = lane&1;
      const float* nr = NSf + row*NSTR + hf*8;
      f32x4 q0 = *(const f32x4*)nr, q1 = *(const f32x4*)(nr+4);
      unsigned w0=pk2h(q0[0],q0[1]), w1=pk2h(q0[2],q0[3]);
      unsigned w2=pk2h(q1[0],q1[1]), w3=pk2h(q1[2],q1[3]);
      unsigned short* sd = H16 + ((size_t)li*513 + (size_t)(t+1))*32768 + row*1024 + wr*16 + hf*8;
      cstore16(sd, w0, w1, w2, w3);
      if (t==T_-1){
        float* op = ostate + (size_t)li*BD_ + (size_t)row*D_ + wr*16 + hf*8;
        *(f32x4*)op = q0; *(f32x4*)(op+4) = q1;
      }
    }

    // ---- arrive: drain stores, WG-sync, one bump
    asm volatile("s_waitcnt vmcnt(0)" ::: "memory");
    __syncthreads();
    if (tid==0)
      __hip_atomic_fetch_add(prog+li*64, 1u, __ATOMIC_RELAXED, __HIP_MEMORY_SCOPE_AGENT);
  }

  // ---- tail: y[511]
  if (li==3){
    WPOLL(prog+3*64, 64u*(unsigned)T_);
    u64 sbS = (u64)(uintptr_t)(H16 + ((size_t)3*513 + (size_t)T_)*32768);
    u32x4 pS[16];
    GLDX(pS[0],  voA+0*256, sbS); GLDX(pS[1],  voB+0*256, sbS);
    GLDX(pS[2],  voA+1*256, sbS); GLDX(pS[3],  voB+1*256, sbS);
    GLDX(pS[4],  voA+2*256, sbS); GLDX(pS[5],  voB+2*256, sbS);
    GLDX(pS[6],  voA+3*256, sbS); GLDX(pS[7],  voB+3*256, sbS);
    GLDX(pS[8],  voA+4*256, sbS); GLDX(pS[9],  voB+4*256, sbS);
    GLDX(pS[10], voA+5*256, sbS); GLDX(pS[11], voB+5*256, sbS);
    GLDX(pS[12], voA+6*256, sbS); GLDX(pS[13], voB+6*256, sbS);
    GLDX(pS[14], voA+7*256, sbS); GLDX(pS[15], voB+7*256, sbS);
    WAITV(0);
    float sS=0.f,qS=0.f,sT=0.f,qT=0.f;
    #pragma unroll
    for (int c2=0;c2<8;++c2){
      f16x8 tA=__builtin_bit_cast(f16x8,pS[2*c2]);
      f16x8 tB=__builtin_bit_cast(f16x8,pS[2*c2+1]);
      #pragma unroll
      for (int j=0;j<8;++j){
        float fa=(float)tA[j], fb=(float)tB[j];
        sS+=fa; qS+=fa*fa; sT+=fb; qT+=fb*fb;
      }
    }
    sS+=__shfl_xor(sS,16); qS+=__shfl_xor(qS,16); sT+=__shfl_xor(sT,16); qT+=__shfl_xor(qT,16);
    sS+=__shfl_xor(sS,32); qS+=__shfl_xor(qS,32); sT+=__shfl_xor(sT,32); qT+=__shfl_xor(qT,32);
    if (lane<16){ f32x4 pk={sS,qS,sT,qT}; *(f32x4*)(RED1+((v*16+lane)<<4))=pk; }
    BARS;
    f32x4 sp0={0.f,0.f,0.f,0.f}, sp1={0.f,0.f,0.f,0.f};
    #pragma unroll
    for (int vv=0;vv<4;++vv){
      sp0 += *(const f32x4*)(RED1+((vv*16+(r0&15))<<4));
      sp1 += *(const f32x4*)(RED1+((vv*16+(r1&15))<<4));
    }
    float gv=SGSB[col], bv=SGSB[16+col];
    float s0=(r0<16)? sp0.x : sp0.z, q0=(r0<16)? sp0.y : sp0.w;
    float m0=s0*(1.f/1024.f);
    float rs0=rsqrtf(q0*(1.f/1024.f)-m0*m0+EPSF);
    y[(size_t)(T_-1)*BD_+(size_t)r0*D_+wr*16+col]=(pns.x-m0)*rs0*gv+bv;
    float s1v=(r1<16)? sp1.x : sp1.z, q1v=(r1<16)? sp1.y : sp1.w;
    float m1=s1v*(1.f/1024.f);
    float rs1=rsqrtf(q1v*(1.f/1024.f)-m1*m1+EPSF);
    y[(size_t)(T_-1)*BD_+(size_t)r1*D_+wr*16+col]=(pns.y-m1)*rs1*gv+bv;
  }
}

extern "C" void kernel_launch(void* const* d_in, const int* in_sizes, int n_in,
                              void* d_out, int out_size, void* d_ws, size_t ws_size,
                              hipStream_t stream){
  (void)in_sizes; (void)n_in; (void)out_size; (void)ws_size;
  const float* x   = (const float*)d_in[0];
  const float* st0 = (const float*)d_in[1];
  const float* Wf  = (const float*)d_in[2];
  const float* Uf  = (const float*)d_in[3];
  const float* bfv = (const float*)d_in[4];
  const float* Wc  = (const float*)d_in[5];
  const float* Uc  = (const float*)d_in[6];
  const float* bcv = (const float*)d_in[7];
  const float* pg  = (const float*)d_in[8];
  const float* pb  = (const float*)d_in[9];
  const float* sg  = (const float*)d_in[10];
  const float* sbv = (const float*)d_in[11];

  float* y      = (float*)d_out;
  float* ostate = y + (size_t)T_*BD_;
  char* ws = (char*)d_ws;

  (void)hipMemsetAsync(ws, 0, 4096, stream);
  hipLaunchKernelGGL(crs_prepass, dim3(8192), dim3(256), 0, stream,
                     Wf, Uf, Wc, Uc, (unsigned short*)(ws+WSO_WT));
  hipLaunchKernelGGL(crs_prep2, dim3(L_), dim3(256), 0, stream,
                     st0, (unsigned short*)(ws+WSO_H16));
  (void)hipFuncSetAttribute((const void*)crs_main, hipFuncAttributeMaxDynamicSharedMemorySize, LDS_TOTAL);
  hipLaunchKernelGGL(crs_main, dim3(NWG), dim3(TPB), LDS_TOTAL, stream,
                     x, st0, bfv, bcv, pg, pb, sg, sbv, y, ostate,
                     (const unsigned short*)(ws+WSO_WT), ws);
}

// Round 16
// 5474.154 us; speedup vs baseline: 1.3944x; 1.3944x over previous
//
#include <hip/hip_runtime.h>
#include <cstdint>
#include <cstddef>

#define T_ 512
#define B_ 32
#define D_ 1024
#define L_ 4
#define BD_ (B_*D_)
#define TPB 256
#define NWG 256
#define EPSF 1e-5f

typedef _Float16 f16x8 __attribute__((ext_vector_type(8)));
typedef float f32x4 __attribute__((ext_vector_type(4)));
typedef float f32x2 __attribute__((ext_vector_type(2)));
typedef unsigned int u32x4 __attribute__((ext_vector_type(4)));
typedef unsigned long long u64;

// workspace layout (bytes)
#define WSO_PROG   0          // 4 layer progress counters, 256B apart (memset 4096)
#define WSO_WT     1048576    // fp16 weights, 32MB
#define WSO_H16    34603008   // [4][513][32][1024] fp16 state/h streams

// LDS layout (bytes)
#define LDS_W     0
#define LDS_DUMP  131072
#define LDS_GB    147456
#define LDS_NS    155904
#define LDS_BIAS  158464
#define LDS_SGSB  158592
#define LDS_RED   158720
#define LDS_TOTAL 160768
#define NSTR 20

__device__ __forceinline__ unsigned pk2h(float a, float b){
  _Float16 ha=(_Float16)a, hb=(_Float16)b;
  return (unsigned)__builtin_bit_cast(unsigned short,ha) |
         ((unsigned)__builtin_bit_cast(unsigned short,hb)<<16);
}
__device__ __forceinline__ unsigned cldu(const unsigned* p){
  return __hip_atomic_load(p,__ATOMIC_RELAXED,__HIP_MEMORY_SCOPE_AGENT);
}
__device__ __forceinline__ void cstore16(unsigned short* p, unsigned w0, unsigned w1, unsigned w2, unsigned w3){
  u64 lo=((u64)w1<<32)|w0, hi=((u64)w3<<32)|w2;
  __hip_atomic_store((u64*)(void*)p,     lo, __ATOMIC_RELAXED, __HIP_MEMORY_SCOPE_AGENT);
  __hip_atomic_store((u64*)(void*)(p+4), hi, __ATOMIC_RELAXED, __HIP_MEMORY_SCOPE_AGENT);
}

#define GLDX(d,vo,sb)  asm volatile("global_load_dwordx4 %0, %1, %2" : "=v"(d) : "v"(vo), "s"(sb) : "memory")
#define WAITV(N) do{ asm volatile("s_waitcnt vmcnt(" #N ")" ::: "memory"); __builtin_amdgcn_sched_barrier(0); }while(0)
#define BARS do{ asm volatile("s_waitcnt lgkmcnt(0)" ::: "memory"); __builtin_amdgcn_s_barrier(); }while(0)
#define WAITL do{ asm volatile("s_waitcnt lgkmcnt(0)" ::: "memory"); __builtin_amdgcn_sched_barrier(0); }while(0)
#define DRAINV do{ asm volatile("s_waitcnt vmcnt(0)" ::: "memory"); __builtin_amdgcn_sched_barrier(0); }while(0)

#define MM(cc) do{ \
    const int kb_=(((cc)*128+kq))*2; \
    f16x8 bF=*(const f16x8*)(WF + (kb_^swl)); \
    f16x8 bC=*(const f16x8*)(WC + (kb_^swl)); \
    accF0=__builtin_amdgcn_mfma_f32_16x16x32_f16(a0,bF,accF0,0,0,0); \
    accF1=__builtin_amdgcn_mfma_f32_16x16x32_f16(a1,bF,accF1,0,0,0); \
    accC0=__builtin_amdgcn_mfma_f32_16x16x32_f16(a0,bC,accC0,0,0,0); \
    accC1=__builtin_amdgcn_mfma_f32_16x16x32_f16(a1,bC,accC1,0,0,0); \
  }while(0)

// state chunk i (fused-k chunk 8+i): raw fp16; prefetched h/x are OLDER in the vm queue
#define PSI(i,NW) do{ WAITV(NW); \
    f16x8 a0=__builtin_bit_cast(f16x8,pS[2*(i)]); \
    f16x8 a1=__builtin_bit_cast(f16x8,pS[2*(i)+1]); \
    MM(8+(i)); }while(0)

// h chunk c (li>0): fp16 + packed-fp16 LN; pP already landed
#define PHN(c) do{ \
    f16x8 a0=__builtin_bit_cast(f16x8,pP[2*(c)]); \
    f16x8 a1=__builtin_bit_cast(f16x8,pP[2*(c)+1]); \
    const int kf_=(c)*128+kq; \
    f16x8 g8=*(const f16x8*)(GBg16+(kf_>>1)); \
    f16x8 b8=*(const f16x8*)(GBg16+512+(kf_>>1)); \
    a0=a0*rsA8+nmA8; a0=a0*g8+b8; \
    a1=a1*rsB8+nmB8; a1=a1*g8+b8; \
    MM(c); }while(0)

// x chunk c (li==0): fp32 + f32 LN; pP already landed
#define PHX(c) do{ \
    f32x4 xa0=__builtin_bit_cast(f32x4,pP[4*(c)]),   xa1=__builtin_bit_cast(f32x4,pP[4*(c)+1]); \
    f32x4 xb0=__builtin_bit_cast(f32x4,pP[4*(c)+2]), xb1=__builtin_bit_cast(f32x4,pP[4*(c)+3]); \
    const int kf_=(c)*128+kq; \
    f32x4 g0=*(const f32x4*)(GBg32+kf_), g1=*(const f32x4*)(GBg32+kf_+4); \
    f32x4 q0=*(const f32x4*)(GBg32+1024+kf_), q1=*(const f32x4*)(GBg32+1024+kf_+4); \
    f16x8 a0,a1; \
    a0[0]=(_Float16)((xa0[0]*rsA+nmA)*g0[0]+q0[0]); a0[1]=(_Float16)((xa0[1]*rsA+nmA)*g0[1]+q0[1]); \
    a0[2]=(_Float16)((xa0[2]*rsA+nmA)*g0[2]+q0[2]); a0[3]=(_Float16)((xa0[3]*rsA+nmA)*g0[3]+q0[3]); \
    a0[4]=(_Float16)((xa1[0]*rsA+nmA)*g1[0]+q1[0]); a0[5]=(_Float16)((xa1[1]*rsA+nmA)*g1[1]+q1[1]); \
    a0[6]=(_Float16)((xa1[2]*rsA+nmA)*g1[2]+q1[2]); a0[7]=(_Float16)((xa1[3]*rsA+nmA)*g1[3]+q1[3]); \
    a1[0]=(_Float16)((xb0[0]*rsB+nmB)*g0[0]+q0[0]); a1[1]=(_Float16)((xb0[1]*rsB+nmB)*g0[1]+q0[1]); \
    a1[2]=(_Float16)((xb0[2]*rsB+nmB)*g0[2]+q0[2]); a1[3]=(_Float16)((xb0[3]*rsB+nmB)*g0[3]+q0[3]); \
    a1[4]=(_Float16)((xb1[0]*rsB+nmB)*g1[0]+q1[0]); a1[5]=(_Float16)((xb1[1]*rsB+nmB)*g1[1]+q1[1]); \
    a1[6]=(_Float16)((xb1[2]*rsB+nmB)*g1[2]+q1[2]); a1[7]=(_Float16)((xb1[3]*rsB+nmB)*g1[3]+q1[3]); \
    MM(c); }while(0)

#define LOAD_STATE(sb) do{ \
  GLDX(pS[0],  voA+0*256, sb); GLDX(pS[1],  voB+0*256, sb); \
  GLDX(pS[2],  voA+1*256, sb); GLDX(pS[3],  voB+1*256, sb); \
  GLDX(pS[4],  voA+2*256, sb); GLDX(pS[5],  voB+2*256, sb); \
  GLDX(pS[6],  voA+3*256, sb); GLDX(pS[7],  voB+3*256, sb); \
  GLDX(pS[8],  voA+4*256, sb); GLDX(pS[9],  voB+4*256, sb); \
  GLDX(pS[10], voA+5*256, sb); GLDX(pS[11], voB+5*256, sb); \
  GLDX(pS[12], voA+6*256, sb); GLDX(pS[13], voB+6*256, sb); \
  GLDX(pS[14], voA+7*256, sb); GLDX(pS[15], voB+7*256, sb); \
}while(0)

#define LOAD_H(sb) do{ \
  GLDX(pP[0],  voA+0*256, sb); GLDX(pP[1],  voB+0*256, sb); \
  GLDX(pP[2],  voA+1*256, sb); GLDX(pP[3],  voB+1*256, sb); \
  GLDX(pP[4],  voA+2*256, sb); GLDX(pP[5],  voB+2*256, sb); \
  GLDX(pP[6],  voA+3*256, sb); GLDX(pP[7],  voB+3*256, sb); \
  GLDX(pP[8],  voA+4*256, sb); GLDX(pP[9],  voB+4*256, sb); \
  GLDX(pP[10], voA+5*256, sb); GLDX(pP[11], voB+5*256, sb); \
  GLDX(pP[12], voA+6*256, sb); GLDX(pP[13], voB+6*256, sb); \
  GLDX(pP[14], voA+7*256, sb); GLDX(pP[15], voB+7*256, sb); \
}while(0)

#define LOAD_X(sb) do{ \
  GLDX(pP[0],  vxA+0*512, sb); GLDX(pP[1],  vxA+0*512+16, sb); GLDX(pP[2],  vxB+0*512, sb); GLDX(pP[3],  vxB+0*512+16, sb); \
  GLDX(pP[4],  vxA+1*512, sb); GLDX(pP[5],  vxA+1*512+16, sb); GLDX(pP[6],  vxB+1*512, sb); GLDX(pP[7],  vxB+1*512+16, sb); \
  GLDX(pP[8],  vxA+2*512, sb); GLDX(pP[9],  vxA+2*512+16, sb); GLDX(pP[10], vxB+2*512, sb); GLDX(pP[11], vxB+2*512+16, sb); \
  GLDX(pP[12], vxA+3*512, sb); GLDX(pP[13], vxA+3*512+16, sb); GLDX(pP[14], vxB+3*512, sb); GLDX(pP[15], vxB+3*512+16, sb); \
  GLDX(pP[16], vxA+4*512, sb); GLDX(pP[17], vxA+4*512+16, sb); GLDX(pP[18], vxB+4*512, sb); GLDX(pP[19], vxB+4*512+16, sb); \
  GLDX(pP[20], vxA+5*512, sb); GLDX(pP[21], vxA+5*512+16, sb); GLDX(pP[22], vxB+5*512, sb); GLDX(pP[23], vxB+5*512+16, sb); \
  GLDX(pP[24], vxA+6*512, sb); GLDX(pP[25], vxA+6*512+16, sb); GLDX(pP[26], vxB+6*512, sb); GLDX(pP[27], vxB+6*512+16, sb); \
  GLDX(pP[28], vxA+7*512, sb); GLDX(pP[29], vxA+7*512+16, sb); GLDX(pP[30], vxB+7*512, sb); GLDX(pP[31], vxB+7*512+16, sb); \
}while(0)

// ---------------- pre-pass 1: weights -> fp16 transposed fused layout ----------------
extern "C" __global__ void __launch_bounds__(256,1) crs_prepass(
    const float* __restrict__ Wf, const float* __restrict__ Uf,
    const float* __restrict__ Wc, const float* __restrict__ Uc,
    unsigned short* __restrict__ WT)
{
  int bid = blockIdx.x;
  int kt  = bid & 15;
  int ct  = (bid>>4) & 31;
  int sel = (bid>>9) & 3;
  int i   = bid >> 11;
  int tid = threadIdx.x;
  int kq  = tid >> 5;
  int cc  = tid & 31;
  const float* sp;
  if      (sel==0) sp = Wf;
  else if (sel==1) sp = Uf;
  else if (sel==2) sp = Wc;
  else             sp = Uc;
  sp += (size_t)i * 1048576;
  int cl = ct*32 + cc;
  int k0 = kt*64 + kq*8;
  float f[8];
  #pragma unroll
  for (int e=0;e<8;++e){ f[e] = sp[(size_t)(k0+e)*1024 + cl]; }
  int cg = ((sel>>1) ? 1024 : 0) + cl;
  int ks = sel & 1;
  size_t idx = ((size_t)(i*2048 + cg)*2 + ks)*1024 + k0;
  uint4 pk;
  pk.x = pk2h(f[0], f[1]);
  pk.y = pk2h(f[2], f[3]);
  pk.z = pk2h(f[4], f[5]);
  pk.w = pk2h(f[6], f[7]);
  *(uint4*)(WT + idx) = pk;
}

// ---------------- pre-pass 2: initial state -> H16 slot 0 ----------------
extern "C" __global__ void __launch_bounds__(256,1) crs_prep2(
    const float* __restrict__ st0, unsigned short* __restrict__ H16)
{
  int i2=blockIdx.x, tid=threadIdx.x;
  int rr=tid>>3, ss=tid&7;
  const float4* p4=(const float4*)(st0+(size_t)i2*BD_+rr*1024+ss*128);
  uint4* dst=(uint4*)(H16+(size_t)i2*513*32768+rr*1024+ss*128);
  #pragma unroll
  for (int q=0;q<16;++q){
    float4 a=p4[2*q], b=p4[2*q+1];
    uint4 pk; pk.x=pk2h(a.x,a.y); pk.y=pk2h(a.z,a.w); pk.z=pk2h(b.x,b.y); pk.w=pk2h(b.z,b.w);
    dst[q]=pk;
  }
}

// ---------------- main persistent kernel ----------------
extern "C" __global__ void __launch_bounds__(TPB,1) crs_main(
    const float* __restrict__ x, const float* __restrict__ st0,
    const float* __restrict__ bfv, const float* __restrict__ bcv,
    const float* __restrict__ pg, const float* __restrict__ pb,
    const float* __restrict__ sg, const float* __restrict__ sbv,
    float* __restrict__ y, float* __restrict__ ostate,
    const unsigned short* __restrict__ WT, char* __restrict__ ws)
{
  extern __shared__ char smem[];
  const int tid=threadIdx.x, w=blockIdx.x;
  const int li=w>>6, wr=w&63;
  const int lane=tid&63, v=tid>>6;
  const int l15=lane&15, lg=(lane>>4)&3;
  const int kq = v*32 + lg*8;
  const int col=lane&15, rp=lane>>4;
  const int r0=v*8+rp, r1=v*8+4+rp;
  const int sseg=tid&7;

  unsigned* prog=(unsigned*)(ws+WSO_PROG);
  unsigned short* H16=(unsigned short*)(ws+WSO_H16);
  float* NSf=(float*)(smem+LDS_NS);
  float* BIAS=(float*)(smem+LDS_BIAS);
  float* SGSB=(float*)(smem+LDS_SGSB);
  char* RED0=smem+LDS_RED;
  char* RED1=smem+LDS_RED+1024;

  // one-time init: weights -> LDS
  {
    int lc=tid>>3;
    int cgl=(lc>>4)*1024 + wr*16 + (lc&15);
    const unsigned short* src=WT + ((size_t)li*2048+cgl)*2048;
    char* dcol = smem + LDS_W + lc*4096;
    int sw2=(lc&7)<<4;
    #pragma unroll
    for (int n=0;n<32;++n){
      int q=sseg+n*8;
      uint4 d=*(const uint4*)(src+q*8);
      *(uint4*)(dcol + ((q*16)^sw2)) = d;
    }
  }
  if (li==0){
    float* g32=(float*)(smem+LDS_GB);
    for (int k=tid;k<1024;k+=TPB){ g32[k]=pg[k]; g32[1024+k]=pb[k]; }
  } else {
    unsigned* g16=(unsigned*)(smem+LDS_GB);
    for (int k=tid;k<512;k+=TPB){
      g16[k]    =pk2h(pg[li*1024+2*k], pg[li*1024+2*k+1]);
      g16[512+k]=pk2h(pb[li*1024+2*k], pb[li*1024+2*k+1]);
    }
  }
  if (tid<16) BIAS[tid]=bfv[li*1024+wr*16+tid];
  else if (tid<32) BIAS[tid]=bcv[li*1024+wr*16+(tid-16)];
  if (li==3){
    if (tid<16) SGSB[tid]=sg[wr*16+tid];
    else if (tid<32) SGSB[tid]=sbv[wr*16+(tid-16)];
  }
  f32x2 sreg, pns={0.f,0.f};
  sreg.x = st0[(size_t)li*BD_ + (size_t)r0*D_ + wr*16+col];
  sreg.y = st0[(size_t)li*BD_ + (size_t)r1*D_ + wr*16+col];
  __syncthreads();

  const char* WF = smem + LDS_W + l15*4096;
  const char* WC = smem + LDS_W + (16+l15)*4096;
  const int swl = (l15&7)<<4;
  const unsigned* GBg16 = (const unsigned*)(smem+LDS_GB);
  const float* GBg32 = (const float*)(smem+LDS_GB);
  const int voA = l15*2048 + kq*2, voB = voA + 32768;
  const int vxA = l15*4096 + kq*4, vxB = vxA + 65536;

  u32x4 pP[32];   // li0: x payload (32); li>0: h payload (16) — persists across steps
  u32x4 pS[16];

  // ---- prologue prefetch for t=0
  if (li==0){
    u64 sbH=(u64)(uintptr_t)x;
    LOAD_X(sbH);
  } else {
    if (tid==0){ while (cldu(prog+(li-1)*64) < 64u) __builtin_amdgcn_s_sleep(1); }
    BARS;
    u64 sbH=(u64)(uintptr_t)(H16 + ((size_t)(li-1)*513 + 1)*32768);
    LOAD_H(sbH);
  }

  for (int t=0; t<T_; ++t){
    // ---- poll 1 (tid0): own-layer state(t) ready; raw barrier broadcast (no vm drain)
    if (tid==0){
      const unsigned ow=64u*(unsigned)t;
      while (cldu(prog+li*64) < ow) __builtin_amdgcn_s_sleep(1);
    }
    BARS;

    u64 sbS = (u64)(uintptr_t)(H16 + ((size_t)li*513 + (size_t)t)*32768);
    LOAD_STATE(sbS);

    f32x4 accF0={0,0,0,0}, accF1={0,0,0,0}, accC0={0,0,0,0}, accC1={0,0,0,0};
    // state chunks: h/x prefetch is OLDER in queue → waits 14..0
    PSI(0,14); PSI(1,12); PSI(2,10); PSI(3,8); PSI(4,6); PSI(5,4); PSI(6,2); PSI(7,0);
    WAITV(0);

    if (li==0){
      float sA=0.f,qA=0.f,sB=0.f,qB=0.f;
      #pragma unroll
      for (int c2=0;c2<8;++c2){
        f32x4 u0=__builtin_bit_cast(f32x4,pP[4*c2]),   u1=__builtin_bit_cast(f32x4,pP[4*c2+1]);
        f32x4 w0=__builtin_bit_cast(f32x4,pP[4*c2+2]), w1=__builtin_bit_cast(f32x4,pP[4*c2+3]);
        #pragma unroll
        for (int j=0;j<4;++j){
          sA+=u0[j]; qA+=u0[j]*u0[j]; sA+=u1[j]; qA+=u1[j]*u1[j];
          sB+=w0[j]; qB+=w0[j]*w0[j]; sB+=w1[j]; qB+=w1[j]*w1[j];
        }
      }
      sA+=__shfl_xor(sA,16); qA+=__shfl_xor(qA,16); sB+=__shfl_xor(sB,16); qB+=__shfl_xor(qB,16);
      sA+=__shfl_xor(sA,32); qA+=__shfl_xor(qA,32); sB+=__shfl_xor(sB,32); qB+=__shfl_xor(qB,32);
      if (lane<16){ f32x4 pk={sA,qA,sB,qB}; *(f32x4*)(RED0+((v*16+lane)<<4))=pk; }
      BARS;
      f32x4 hp={0.f,0.f,0.f,0.f};
      #pragma unroll
      for (int vv=0;vv<4;++vv) hp += *(const f32x4*)(RED0+((vv*16+l15)<<4));
      float mA=hp.x*(1.f/1024.f);
      float rsA=rsqrtf(hp.y*(1.f/1024.f)-mA*mA+EPSF), nmA=-mA*rsA;
      float mB=hp.z*(1.f/1024.f);
      float rsB=rsqrtf(hp.w*(1.f/1024.f)-mB*mB+EPSF), nmB=-mB*rsB;
      PHX(0); PHX(1); PHX(2); PHX(3); PHX(4); PHX(5); PHX(6); PHX(7);
    } else {
      float sA=0.f,qA=0.f,sB=0.f,qB=0.f;
      #pragma unroll
      for (int c2=0;c2<8;++c2){
        f16x8 hA=__builtin_bit_cast(f16x8,pP[2*c2]);
        f16x8 hB=__builtin_bit_cast(f16x8,pP[2*c2+1]);
        #pragma unroll
        for (int j=0;j<8;++j){
          float fa=(float)hA[j], fb=(float)hB[j];
          sA+=fa; qA+=fa*fa; sB+=fb; qB+=fb*fb;
        }
      }
      sA+=__shfl_xor(sA,16); qA+=__shfl_xor(qA,16); sB+=__shfl_xor(sB,16); qB+=__shfl_xor(qB,16);
      sA+=__shfl_xor(sA,32); qA+=__shfl_xor(qA,32); sB+=__shfl_xor(sB,32); qB+=__shfl_xor(qB,32);
      if (lane<16){ f32x4 pk={sA,qA,sB,qB}; *(f32x4*)(RED0+((v*16+lane)<<4))=pk; }
      if (li==3){
        float sS=0.f,qS=0.f,sT=0.f,qT=0.f;
        #pragma unroll
        for (int c2=0;c2<8;++c2){
          f16x8 tA=__builtin_bit_cast(f16x8,pS[2*c2]);
          f16x8 tB=__builtin_bit_cast(f16x8,pS[2*c2+1]);
          #pragma unroll
          for (int j=0;j<8;++j){
            float fa=(float)tA[j], fb=(float)tB[j];
            sS+=fa; qS+=fa*fa; sT+=fb; qT+=fb*fb;
          }
        }
        sS+=__shfl_xor(sS,16); qS+=__shfl_xor(qS,16); sT+=__shfl_xor(sT,16); qT+=__shfl_xor(qT,16);
        sS+=__shfl_xor(sS,32); qS+=__shfl_xor(qS,32); sT+=__shfl_xor(sT,32); qT+=__shfl_xor(qT,32);
        if (lane<16){ f32x4 pk={sS,qS,sT,qT}; *(f32x4*)(RED1+((v*16+lane)<<4))=pk; }
      }
      BARS;
      f32x4 hp={0.f,0.f,0.f,0.f};
      #pragma unroll
      for (int vv=0;vv<4;++vv) hp += *(const f32x4*)(RED0+((vv*16+l15)<<4));
      float mAf=hp.x*(1.f/1024.f);
      float rsAf=rsqrtf(hp.y*(1.f/1024.f)-mAf*mAf+EPSF), nmAf=-mAf*rsAf;
      float mBf=hp.z*(1.f/1024.f);
      float rsBf=rsqrtf(hp.w*(1.f/1024.f)-mBf*mBf+EPSF), nmBf=-mBf*rsBf;
      const _Float16 hrA=(_Float16)rsAf, hmA=(_Float16)nmAf, hrB=(_Float16)rsBf, hmB=(_Float16)nmBf;
      const f16x8 rsA8={hrA,hrA,hrA,hrA,hrA,hrA,hrA,hrA};
      const f16x8 nmA8={hmA,hmA,hmA,hmA,hmA,hmA,hmA,hmA};
      const f16x8 rsB8={hrB,hrB,hrB,hrB,hrB,hrB,hrB,hrB};
      const f16x8 nmB8={hmB,hmB,hmB,hmB,hmB,hmB,hmB,hmB};
      if (li==3 && t>=1){
        f32x4 sp0={0.f,0.f,0.f,0.f}, sp1={0.f,0.f,0.f,0.f};
        #pragma unroll
        for (int vv=0;vv<4;++vv){
          sp0 += *(const f32x4*)(RED1+((vv*16+(r0&15))<<4));
          sp1 += *(const f32x4*)(RED1+((vv*16+(r1&15))<<4));
        }
        float gv=SGSB[col], bv=SGSB[16+col];
        float s0=(r0<16)? sp0.x : sp0.z, q0=(r0<16)? sp0.y : sp0.w;
        float m0=s0*(1.f/1024.f);
        float rs0=rsqrtf(q0*(1.f/1024.f)-m0*m0+EPSF);
        y[(size_t)(t-1)*BD_+(size_t)r0*D_+wr*16+col]=(pns.x-m0)*rs0*gv+bv;
        float s1v=(r1<16)? sp1.x : sp1.z, q1v=(r1<16)? sp1.y : sp1.w;
        float m1=s1v*(1.f/1024.f);
        float rs1=rsqrtf(q1v*(1.f/1024.f)-m1*m1+EPSF);
        y[(size_t)(t-1)*BD_+(size_t)r1*D_+wr*16+col]=(pns.y-m1)*rs1*gv+bv;
      }
      PHN(0); PHN(1); PHN(2); PHN(3); PHN(4); PHN(5); PHN(6); PHN(7);
    }

    *(f32x4*)(smem+LDS_DUMP + (((v*4+0)*64+lane)<<4)) = accF0;
    *(f32x4*)(smem+LDS_DUMP + (((v*4+1)*64+lane)<<4)) = accF1;
    *(f32x4*)(smem+LDS_DUMP + (((v*4+2)*64+lane)<<4)) = accC0;
    *(f32x4*)(smem+LDS_DUMP + (((v*4+3)*64+lane)<<4)) = accC1;
    BARS;

    {
      const int rtl = v>>1;
      const int lg20 = (v&1)*2, lg21 = (v&1)*2+1;
      float fF0=0.f,fF1=0.f,fC0=0.f,fC1=0.f;
      #pragma unroll
      for (int v2=0;v2<4;++v2){
        const char* db = smem+LDS_DUMP + v2*4096;
        fF0 += *(const float*)(db + (((0+rtl)*64 + lg20*16+col)<<4) + rp*4);
        fF1 += *(const float*)(db + (((0+rtl)*64 + lg21*16+col)<<4) + rp*4);
        fC0 += *(const float*)(db + (((2+rtl)*64 + lg20*16+col)<<4) + rp*4);
        fC1 += *(const float*)(db + (((2+rtl)*64 + lg21*16+col)<<4) + rp*4);
      }
      float bfc=BIAS[col], bcc=BIAS[16+col];
      float preF0=fminf(fmaxf(fF0+bfc,-30.f),30.f);
      float preC0=fminf(fmaxf(fC0+bcc,-30.f),30.f);
      float preF1=fminf(fmaxf(fF1+bfc,-30.f),30.f);
      float preC1=fminf(fmaxf(fC1+bcc,-30.f),30.f);
      float fg0=1.f/(1.f+__expf(-preF0)), e0=__expf(-2.f*preC0);
      float cd0=(1.f-e0)/(1.f+e0);
      float fg1=1.f/(1.f+__expf(-preF1)), e1=__expf(-2.f*preC1);
      float cd1=(1.f-e1)/(1.f+e1);
      float ns0=fg0*sreg.x+(1.f-fg0)*cd0;
      float ns1=fg1*sreg.y+(1.f-fg1)*cd1;
      sreg.x=ns0; sreg.y=ns1;
      if (li==3){ pns.x=ns0; pns.y=ns1; }
      NSf[r0*NSTR+col]=ns0;
      NSf[r1*NSTR+col]=ns1;
    }
    WAITL;   // same-wave NSf rows: intra-wave LDS order suffices

    if (lane<16){
      int row = v*8 + (lane>>1), hf = lane&1;
      const float* nr = NSf + row*NSTR + hf*8;
      f32x4 q0 = *(const f32x4*)nr, q1 = *(const f32x4*)(nr+4);
      unsigned w0=pk2h(q0[0],q0[1]), w1=pk2h(q0[2],q0[3]);
      unsigned w2=pk2h(q1[0],q1[1]), w3=pk2h(q1[2],q1[3]);
      unsigned short* sd = H16 + ((size_t)li*513 + (size_t)(t+1))*32768 + row*1024 + wr*16 + hf*8;
      cstore16(sd, w0, w1, w2, w3);
      if (t==T_-1){
        float* op = ostate + (size_t)li*BD_ + (size_t)row*D_ + wr*16 + hf*8;
        *(f32x4*)op = q0; *(f32x4*)(op+4) = q1;
      }
    }

    // ---- arrive: per-wave store drain, raw barrier, single bump
    DRAINV;
    BARS;
    if (tid==0)
      __hip_atomic_fetch_add(prog+li*64, 1u, __ATOMIC_RELAXED, __HIP_MEMORY_SCOPE_AGENT);

    // ---- prefetch h/x for t+1 (off the own-state critical path)
    if (t+1 < T_){
      if (li==0){
        u64 sbH=(u64)(uintptr_t)(x + (size_t)(t+1)*BD_);
        LOAD_X(sbH);
      } else {
        if (tid==0){
          const unsigned uw=64u*(unsigned)(t+2);
          while (cldu(prog+(li-1)*64) < uw) __builtin_amdgcn_s_sleep(1);
        }
        BARS;
        u64 sbH=(u64)(uintptr_t)(H16 + ((size_t)(li-1)*513 + (size_t)(t+2))*32768);
        LOAD_H(sbH);
      }
    }
  }

  // ---- tail: y[511]
  if (li==3){
    if (tid==0){
      while (cldu(prog+3*64) < 64u*(unsigned)T_) __builtin_amdgcn_s_sleep(1);
    }
    BARS;
    u64 sbS = (u64)(uintptr_t)(H16 + ((size_t)3*513 + (size_t)T_)*32768);
    LOAD_STATE(sbS);
    WAITV(0);
    float sS=0.f,qS=0.f,sT=0.f,qT=0.f;
    #pragma unroll
    for (int c2=0;c2<8;++c2){
      f16x8 tA=__builtin_bit_cast(f16x8,pS[2*c2]);
      f16x8 tB=__builtin_bit_cast(f16x8,pS[2*c2+1]);
      #pragma unroll
      for (int j=0;j<8;++j){
        float fa=(float)tA[j], fb=(float)tB[j];
        sS+=fa; qS+=fa*fa; sT+=fb; qT+=fb*fb;
      }
    }
    sS+=__shfl_xor(sS,16); qS+=__shfl_xor(qS,16); sT+=__shfl_xor(sT,16); qT+=__shfl_xor(qT,16);
    sS+=__shfl_xor(sS,32); qS+=__shfl_xor(qS,32); sT+=__shfl_xor(sT,32); qT+=__shfl_xor(qT,32);
    if (lane<16){ f32x4 pk={sS,qS,sT,qT}; *(f32x4*)(RED1+((v*16+lane)<<4))=pk; }
    BARS;
    f32x4 sp0={0.f,0.f,0.f,0.f}, sp1={0.f,0.f,0.f,0.f};
    #pragma unroll
    for (int vv=0;vv<4;++vv){
      sp0 += *(const f32x4*)(RED1+((vv*16+(r0&15))<<4));
      sp1 += *(const f32x4*)(RED1+((vv*16+(r1&15))<<4));
    }
    float gv=SGSB[col], bv=SGSB[16+col];
    float s0=(r0<16)? sp0.x : sp0.z, q0=(r0<16)? sp0.y : sp0.w;
    float m0=s0*(1.f/1024.f);
    float rs0=rsqrtf(q0*(1.f/1024.f)-m0*m0+EPSF);
    y[(size_t)(T_-1)*BD_+(size_t)r0*D_+wr*16+col]=(pns.x-m0)*rs0*gv+bv;
    float s1v=(r1<16)? sp1.x : sp1.z, q1v=(r1<16)? sp1.y : sp1.w;
    float m1=s1v*(1.f/1024.f);
    float rs1=rsqrtf(q1v*(1.f/1024.f)-m1*m1+EPSF);
    y[(size_t)(T_-1)*BD_+(size_t)r1*D_+wr*16+col]=(pns.y-m1)*rs1*gv+bv;
  }
}

extern "C" void kernel_launch(void* const* d_in, const int* in_sizes, int n_in,
                              void* d_out, int out_size, void* d_ws, size_t ws_size,
                              hipStream_t stream){
  (void)in_sizes; (void)n_in; (void)out_size; (void)ws_size;
  const float* x   = (const float*)d_in[0];
  const float* st0 = (const float*)d_in[1];
  const float* Wf  = (const float*)d_in[2];
  const float* Uf  = (const float*)d_in[3];
  const float* bfv = (const float*)d_in[4];
  const float* Wc  = (const float*)d_in[5];
  const float* Uc  = (const float*)d_in[6];
  const float* bcv = (const float*)d_in[7];
  const float* pg  = (const float*)d_in[8];
  const float* pb  = (const float*)d_in[9];
  const float* sg  = (const float*)d_in[10];
  const float* sbv = (const float*)d_in[11];

  float* y      = (float*)d_out;
  float* ostate = y + (size_t)T_*BD_;
  char* ws = (char*)d_ws;

  (void)hipMemsetAsync(ws, 0, 4096, stream);
  hipLaunchKernelGGL(crs_prepass, dim3(8192), dim3(256), 0, stream,
                     Wf, Uf, Wc, Uc, (unsigned short*)(ws+WSO_WT));
  hipLaunchKernelGGL(crs_prep2, dim3(L_), dim3(256), 0, stream,
                     st0, (unsigned short*)(ws+WSO_H16));
  (void)hipFuncSetAttribute((const void*)crs_main, hipFuncAttributeMaxDynamicSharedMemorySize, LDS_TOTAL);
  hipLaunchKernelGGL(crs_main, dim3(NWG), dim3(TPB), LDS_TOTAL, stream,
                     x, st0, bfv, bcv, pg, pb, sg, sbv, y, ostate,
                     (const unsigned short*)(ws+WSO_WT), ws);
}

// Round 17
// 5093.896 us; speedup vs baseline: 1.4985x; 1.0746x over previous
//
#include <hip/hip_runtime.h>
#include <cstdint>
#include <cstddef>

#define T_ 512
#define B_ 32
#define D_ 1024
#define L_ 4
#define BD_ (B_*D_)
#define TPB 256
#define NWG 256
#define EPSF 1e-5f

typedef _Float16 f16x8 __attribute__((ext_vector_type(8)));
typedef float f32x4 __attribute__((ext_vector_type(4)));
typedef float f32x2 __attribute__((ext_vector_type(2)));
typedef unsigned int u32x4 __attribute__((ext_vector_type(4)));
typedef unsigned long long u64;

// workspace layout (bytes)
#define WSO_PROG   0          // [4][8] arrival counters, 64B apart (memset 4096)
#define WSO_WT     1048576    // fp16 weights, 32MB
#define WSO_H16    34603008   // [4][513][32][1024] fp16 state/h streams

// LDS layout (bytes)
#define LDS_W     0
#define LDS_DUMP  131072
#define LDS_GB    147456
#define LDS_NS    155904
#define LDS_BIAS  158464
#define LDS_SGSB  158592
#define LDS_RED   158720
#define LDS_TOTAL 160768
#define NSTR 20

__device__ __forceinline__ unsigned pk2h(float a, float b){
  _Float16 ha=(_Float16)a, hb=(_Float16)b;
  return (unsigned)__builtin_bit_cast(unsigned short,ha) |
         ((unsigned)__builtin_bit_cast(unsigned short,hb)<<16);
}
__device__ __forceinline__ unsigned cldu(const unsigned* p){
  return __hip_atomic_load(p,__ATOMIC_RELAXED,__HIP_MEMORY_SCOPE_AGENT);
}
// poll 8 split counters (64B apart); 8 independent loads -> one RTT per iteration
__device__ __forceinline__ void poll8(const unsigned* base, unsigned tgt){
  for(;;){
    unsigned c0=cldu(base+0*16), c1=cldu(base+1*16);
    unsigned c2=cldu(base+2*16), c3=cldu(base+3*16);
    unsigned c4=cldu(base+4*16), c5=cldu(base+5*16);
    unsigned c6=cldu(base+6*16), c7=cldu(base+7*16);
    unsigned m=c0;
    m=(c1<m)?c1:m; m=(c2<m)?c2:m; m=(c3<m)?c3:m;
    m=(c4<m)?c4:m; m=(c5<m)?c5:m; m=(c6<m)?c6:m; m=(c7<m)?c7:m;
    if (m>=tgt) break;
    __builtin_amdgcn_s_sleep(1);
  }
}
__device__ __forceinline__ void cstore16(unsigned short* p, unsigned w0, unsigned w1, unsigned w2, unsigned w3){
  u64 lo=((u64)w1<<32)|w0, hi=((u64)w3<<32)|w2;
  __hip_atomic_store((u64*)(void*)p,     lo, __ATOMIC_RELAXED, __HIP_MEMORY_SCOPE_AGENT);
  __hip_atomic_store((u64*)(void*)(p+4), hi, __ATOMIC_RELAXED, __HIP_MEMORY_SCOPE_AGENT);
}

#define GLDX(d,vo,sb)  asm volatile("global_load_dwordx4 %0, %1, %2" : "=v"(d) : "v"(vo), "s"(sb) : "memory")
#define WAITV(N) do{ asm volatile("s_waitcnt vmcnt(" #N ")" ::: "memory"); __builtin_amdgcn_sched_barrier(0); }while(0)
#define BARS do{ asm volatile("s_waitcnt lgkmcnt(0)" ::: "memory"); __builtin_amdgcn_s_barrier(); }while(0)
#define WAITL do{ asm volatile("s_waitcnt lgkmcnt(0)" ::: "memory"); __builtin_amdgcn_sched_barrier(0); }while(0)
#define DRAINV do{ asm volatile("s_waitcnt vmcnt(0)" ::: "memory"); __builtin_amdgcn_sched_barrier(0); }while(0)

#define MM(cc) do{ \
    const int kb_=(((cc)*128+kq))*2; \
    f16x8 bF=*(const f16x8*)(WF + (kb_^swl)); \
    f16x8 bC=*(const f16x8*)(WC + (kb_^swl)); \
    accF0=__builtin_amdgcn_mfma_f32_16x16x32_f16(a0,bF,accF0,0,0,0); \
    accF1=__builtin_amdgcn_mfma_f32_16x16x32_f16(a1,bF,accF1,0,0,0); \
    accC0=__builtin_amdgcn_mfma_f32_16x16x32_f16(a0,bC,accC0,0,0,0); \
    accC1=__builtin_amdgcn_mfma_f32_16x16x32_f16(a1,bC,accC1,0,0,0); \
  }while(0)

// state chunk i (fused-k chunk 8+i): raw fp16; prefetched h/x are OLDER in the vm queue
#define PSI(i,NW) do{ WAITV(NW); \
    f16x8 a0=__builtin_bit_cast(f16x8,pS[2*(i)]); \
    f16x8 a1=__builtin_bit_cast(f16x8,pS[2*(i)+1]); \
    MM(8+(i)); }while(0)

// h chunk c (li>0): fp16 + packed-fp16 LN; pP already landed
#define PHN(c) do{ \
    f16x8 a0=__builtin_bit_cast(f16x8,pP[2*(c)]); \
    f16x8 a1=__builtin_bit_cast(f16x8,pP[2*(c)+1]); \
    const int kf_=(c)*128+kq; \
    f16x8 g8=*(const f16x8*)(GBg16+(kf_>>1)); \
    f16x8 b8=*(const f16x8*)(GBg16+512+(kf_>>1)); \
    a0=a0*rsA8+nmA8; a0=a0*g8+b8; \
    a1=a1*rsB8+nmB8; a1=a1*g8+b8; \
    MM(c); }while(0)

// x chunk c (li==0): fp32 + f32 LN; pP already landed
#define PHX(c) do{ \
    f32x4 xa0=__builtin_bit_cast(f32x4,pP[4*(c)]),   xa1=__builtin_bit_cast(f32x4,pP[4*(c)+1]); \
    f32x4 xb0=__builtin_bit_cast(f32x4,pP[4*(c)+2]), xb1=__builtin_bit_cast(f32x4,pP[4*(c)+3]); \
    const int kf_=(c)*128+kq; \
    f32x4 g0=*(const f32x4*)(GBg32+kf_), g1=*(const f32x4*)(GBg32+kf_+4); \
    f32x4 q0=*(const f32x4*)(GBg32+1024+kf_), q1=*(const f32x4*)(GBg32+1024+kf_+4); \
    f16x8 a0,a1; \
    a0[0]=(_Float16)((xa0[0]*rsA+nmA)*g0[0]+q0[0]); a0[1]=(_Float16)((xa0[1]*rsA+nmA)*g0[1]+q0[1]); \
    a0[2]=(_Float16)((xa0[2]*rsA+nmA)*g0[2]+q0[2]); a0[3]=(_Float16)((xa0[3]*rsA+nmA)*g0[3]+q0[3]); \
    a0[4]=(_Float16)((xa1[0]*rsA+nmA)*g1[0]+q1[0]); a0[5]=(_Float16)((xa1[1]*rsA+nmA)*g1[1]+q1[1]); \
    a0[6]=(_Float16)((xa1[2]*rsA+nmA)*g1[2]+q1[2]); a0[7]=(_Float16)((xa1[3]*rsA+nmA)*g1[3]+q1[3]); \
    a1[0]=(_Float16)((xb0[0]*rsB+nmB)*g0[0]+q0[0]); a1[1]=(_Float16)((xb0[1]*rsB+nmB)*g0[1]+q0[1]); \
    a1[2]=(_Float16)((xb0[2]*rsB+nmB)*g0[2]+q0[2]); a1[3]=(_Float16)((xb0[3]*rsB+nmB)*g0[3]+q0[3]); \
    a1[4]=(_Float16)((xb1[0]*rsB+nmB)*g1[0]+q1[0]); a1[5]=(_Float16)((xb1[1]*rsB+nmB)*g1[1]+q1[1]); \
    a1[6]=(_Float16)((xb1[2]*rsB+nmB)*g1[2]+q1[2]); a1[7]=(_Float16)((xb1[3]*rsB+nmB)*g1[3]+q1[3]); \
    MM(c); }while(0)

#define LOAD_STATE(sb) do{ \
  GLDX(pS[0],  voA+0*256, sb); GLDX(pS[1],  voB+0*256, sb); \
  GLDX(pS[2],  voA+1*256, sb); GLDX(pS[3],  voB+1*256, sb); \
  GLDX(pS[4],  voA+2*256, sb); GLDX(pS[5],  voB+2*256, sb); \
  GLDX(pS[6],  voA+3*256, sb); GLDX(pS[7],  voB+3*256, sb); \
  GLDX(pS[8],  voA+4*256, sb); GLDX(pS[9],  voB+4*256, sb); \
  GLDX(pS[10], voA+5*256, sb); GLDX(pS[11], voB+5*256, sb); \
  GLDX(pS[12], voA+6*256, sb); GLDX(pS[13], voB+6*256, sb); \
  GLDX(pS[14], voA+7*256, sb); GLDX(pS[15], voB+7*256, sb); \
}while(0)

#define LOAD_H(sb) do{ \
  GLDX(pP[0],  voA+0*256, sb); GLDX(pP[1],  voB+0*256, sb); \
  GLDX(pP[2],  voA+1*256, sb); GLDX(pP[3],  voB+1*256, sb); \
  GLDX(pP[4],  voA+2*256, sb); GLDX(pP[5],  voB+2*256, sb); \
  GLDX(pP[6],  voA+3*256, sb); GLDX(pP[7],  voB+3*256, sb); \
  GLDX(pP[8],  voA+4*256, sb); GLDX(pP[9],  voB+4*256, sb); \
  GLDX(pP[10], voA+5*256, sb); GLDX(pP[11], voB+5*256, sb); \
  GLDX(pP[12], voA+6*256, sb); GLDX(pP[13], voB+6*256, sb); \
  GLDX(pP[14], voA+7*256, sb); GLDX(pP[15], voB+7*256, sb); \
}while(0)

#define LOAD_X(sb) do{ \
  GLDX(pP[0],  vxA+0*512, sb); GLDX(pP[1],  vxA+0*512+16, sb); GLDX(pP[2],  vxB+0*512, sb); GLDX(pP[3],  vxB+0*512+16, sb); \
  GLDX(pP[4],  vxA+1*512, sb); GLDX(pP[5],  vxA+1*512+16, sb); GLDX(pP[6],  vxB+1*512, sb); GLDX(pP[7],  vxB+1*512+16, sb); \
  GLDX(pP[8],  vxA+2*512, sb); GLDX(pP[9],  vxA+2*512+16, sb); GLDX(pP[10], vxB+2*512, sb); GLDX(pP[11], vxB+2*512+16, sb); \
  GLDX(pP[12], vxA+3*512, sb); GLDX(pP[13], vxA+3*512+16, sb); GLDX(pP[14], vxB+3*512, sb); GLDX(pP[15], vxB+3*512+16, sb); \
  GLDX(pP[16], vxA+4*512, sb); GLDX(pP[17], vxA+4*512+16, sb); GLDX(pP[18], vxB+4*512, sb); GLDX(pP[19], vxB+4*512+16, sb); \
  GLDX(pP[20], vxA+5*512, sb); GLDX(pP[21], vxA+5*512+16, sb); GLDX(pP[22], vxB+5*512, sb); GLDX(pP[23], vxB+5*512+16, sb); \
  GLDX(pP[24], vxA+6*512, sb); GLDX(pP[25], vxA+6*512+16, sb); GLDX(pP[26], vxB+6*512, sb); GLDX(pP[27], vxB+6*512+16, sb); \
  GLDX(pP[28], vxA+7*512, sb); GLDX(pP[29], vxA+7*512+16, sb); GLDX(pP[30], vxB+7*512, sb); GLDX(pP[31], vxB+7*512+16, sb); \
}while(0)

// ---------------- pre-pass 1: weights -> fp16 transposed fused layout ----------------
extern "C" __global__ void __launch_bounds__(256,1) crs_prepass(
    const float* __restrict__ Wf, const float* __restrict__ Uf,
    const float* __restrict__ Wc, const float* __restrict__ Uc,
    unsigned short* __restrict__ WT)
{
  int bid = blockIdx.x;
  int kt  = bid & 15;
  int ct  = (bid>>4) & 31;
  int sel = (bid>>9) & 3;
  int i   = bid >> 11;
  int tid = threadIdx.x;
  int kq  = tid >> 5;
  int cc  = tid & 31;
  const float* sp;
  if      (sel==0) sp = Wf;
  else if (sel==1) sp = Uf;
  else if (sel==2) sp = Wc;
  else             sp = Uc;
  sp += (size_t)i * 1048576;
  int cl = ct*32 + cc;
  int k0 = kt*64 + kq*8;
  float f[8];
  #pragma unroll
  for (int e=0;e<8;++e){ f[e] = sp[(size_t)(k0+e)*1024 + cl]; }
  int cg = ((sel>>1) ? 1024 : 0) + cl;
  int ks = sel & 1;
  size_t idx = ((size_t)(i*2048 + cg)*2 + ks)*1024 + k0;
  uint4 pk;
  pk.x = pk2h(f[0], f[1]);
  pk.y = pk2h(f[2], f[3]);
  pk.z = pk2h(f[4], f[5]);
  pk.w = pk2h(f[6], f[7]);
  *(uint4*)(WT + idx) = pk;
}

// ---------------- pre-pass 2: initial state -> H16 slot 0 ----------------
extern "C" __global__ void __launch_bounds__(256,1) crs_prep2(
    const float* __restrict__ st0, unsigned short* __restrict__ H16)
{
  int i2=blockIdx.x, tid=threadIdx.x;
  int rr=tid>>3, ss=tid&7;
  const float4* p4=(const float4*)(st0+(size_t)i2*BD_+rr*1024+ss*128);
  uint4* dst=(uint4*)(H16+(size_t)i2*513*32768+rr*1024+ss*128);
  #pragma unroll
  for (int q=0;q<16;++q){
    float4 a=p4[2*q], b=p4[2*q+1];
    uint4 pk; pk.x=pk2h(a.x,a.y); pk.y=pk2h(a.z,a.w); pk.z=pk2h(b.x,b.y); pk.w=pk2h(b.z,b.w);
    dst[q]=pk;
  }
}

// ---------------- main persistent kernel ----------------
extern "C" __global__ void __launch_bounds__(TPB,1) crs_main(
    const float* __restrict__ x, const float* __restrict__ st0,
    const float* __restrict__ bfv, const float* __restrict__ bcv,
    const float* __restrict__ pg, const float* __restrict__ pb,
    const float* __restrict__ sg, const float* __restrict__ sbv,
    float* __restrict__ y, float* __restrict__ ostate,
    const unsigned short* __restrict__ WT, char* __restrict__ ws)
{
  extern __shared__ char smem[];
  const int tid=threadIdx.x, w=blockIdx.x;
  const int li=w>>6, wr=w&63;
  const int lane=tid&63, v=tid>>6;
  const int l15=lane&15, lg=(lane>>4)&3;
  const int kq = v*32 + lg*8;
  const int col=lane&15, rp=lane>>4;
  const int r0=v*8+rp, r1=v*8+4+rp;
  const int sseg=tid&7;

  unsigned* prog=(unsigned*)(ws+WSO_PROG);         // counter (li,g) at prog + (li*8+g)*16
  unsigned* bumpc = prog + (li*8 + (wr>>3))*16;    // this WG's arrival counter
  const unsigned* ownb = prog + (li*8)*16;         // own-layer counter base
  const unsigned* upb  = (li>0)? (prog + ((li-1)*8)*16) : (const unsigned*)0;
  unsigned short* H16=(unsigned short*)(ws+WSO_H16);
  float* NSf=(float*)(smem+LDS_NS);
  float* BIAS=(float*)(smem+LDS_BIAS);
  float* SGSB=(float*)(smem+LDS_SGSB);
  char* RED0=smem+LDS_RED;
  char* RED1=smem+LDS_RED+1024;

  // one-time init: weights -> LDS
  {
    int lc=tid>>3;
    int cgl=(lc>>4)*1024 + wr*16 + (lc&15);
    const unsigned short* src=WT + ((size_t)li*2048+cgl)*2048;
    char* dcol = smem + LDS_W + lc*4096;
    int sw2=(lc&7)<<4;
    #pragma unroll
    for (int n=0;n<32;++n){
      int q=sseg+n*8;
      uint4 d=*(const uint4*)(src+q*8);
      *(uint4*)(dcol + ((q*16)^sw2)) = d;
    }
  }
  if (li==0){
    float* g32=(float*)(smem+LDS_GB);
    for (int k=tid;k<1024;k+=TPB){ g32[k]=pg[k]; g32[1024+k]=pb[k]; }
  } else {
    unsigned* g16=(unsigned*)(smem+LDS_GB);
    for (int k=tid;k<512;k+=TPB){
      g16[k]    =pk2h(pg[li*1024+2*k], pg[li*1024+2*k+1]);
      g16[512+k]=pk2h(pb[li*1024+2*k], pb[li*1024+2*k+1]);
    }
  }
  if (tid<16) BIAS[tid]=bfv[li*1024+wr*16+tid];
  else if (tid<32) BIAS[tid]=bcv[li*1024+wr*16+(tid-16)];
  if (li==3){
    if (tid<16) SGSB[tid]=sg[wr*16+tid];
    else if (tid<32) SGSB[tid]=sbv[wr*16+(tid-16)];
  }
  f32x2 sreg, pns={0.f,0.f};
  sreg.x = st0[(size_t)li*BD_ + (size_t)r0*D_ + wr*16+col];
  sreg.y = st0[(size_t)li*BD_ + (size_t)r1*D_ + wr*16+col];
  __syncthreads();

  const char* WF = smem + LDS_W + l15*4096;
  const char* WC = smem + LDS_W + (16+l15)*4096;
  const int swl = (l15&7)<<4;
  const unsigned* GBg16 = (const unsigned*)(smem+LDS_GB);
  const float* GBg32 = (const float*)(smem+LDS_GB);
  const int voA = l15*2048 + kq*2, voB = voA + 32768;
  const int vxA = l15*4096 + kq*4, vxB = vxA + 65536;

  u32x4 pP[32];   // li0: x payload (32); li>0: h payload (16) — persists across steps
  u32x4 pS[16];

  // ---- prologue prefetch for t=0
  if (li==0){
    u64 sbH=(u64)(uintptr_t)x;
    LOAD_X(sbH);
  } else {
    if (tid==0) poll8(upb, 8u);
    BARS;
    u64 sbH=(u64)(uintptr_t)(H16 + ((size_t)(li-1)*513 + 1)*32768);
    LOAD_H(sbH);
  }

  for (int t=0; t<T_; ++t){
    // ---- poll 1 (tid0): own-layer state(t) ready; raw barrier broadcast (no vm drain)
    if (tid==0) poll8(ownb, 8u*(unsigned)t);
    BARS;

    u64 sbS = (u64)(uintptr_t)(H16 + ((size_t)li*513 + (size_t)t)*32768);
    LOAD_STATE(sbS);

    f32x4 accF0={0,0,0,0}, accF1={0,0,0,0}, accC0={0,0,0,0}, accC1={0,0,0,0};
    // state chunks: h/x prefetch is OLDER in queue → waits 14..0
    PSI(0,14); PSI(1,12); PSI(2,10); PSI(3,8); PSI(4,6); PSI(5,4); PSI(6,2); PSI(7,0);
    WAITV(0);

    if (li==0){
      float sA=0.f,qA=0.f,sB=0.f,qB=0.f;
      #pragma unroll
      for (int c2=0;c2<8;++c2){
        f32x4 u0=__builtin_bit_cast(f32x4,pP[4*c2]),   u1=__builtin_bit_cast(f32x4,pP[4*c2+1]);
        f32x4 w0=__builtin_bit_cast(f32x4,pP[4*c2+2]), w1=__builtin_bit_cast(f32x4,pP[4*c2+3]);
        #pragma unroll
        for (int j=0;j<4;++j){
          sA+=u0[j]; qA+=u0[j]*u0[j]; sA+=u1[j]; qA+=u1[j]*u1[j];
          sB+=w0[j]; qB+=w0[j]*w0[j]; sB+=w1[j]; qB+=w1[j]*w1[j];
        }
      }
      sA+=__shfl_xor(sA,16); qA+=__shfl_xor(qA,16); sB+=__shfl_xor(sB,16); qB+=__shfl_xor(qB,16);
      sA+=__shfl_xor(sA,32); qA+=__shfl_xor(qA,32); sB+=__shfl_xor(sB,32); qB+=__shfl_xor(qB,32);
      if (lane<16){ f32x4 pk={sA,qA,sB,qB}; *(f32x4*)(RED0+((v*16+lane)<<4))=pk; }
      BARS;
      f32x4 hp={0.f,0.f,0.f,0.f};
      #pragma unroll
      for (int vv=0;vv<4;++vv) hp += *(const f32x4*)(RED0+((vv*16+l15)<<4));
      float mA=hp.x*(1.f/1024.f);
      float rsA=rsqrtf(hp.y*(1.f/1024.f)-mA*mA+EPSF), nmA=-mA*rsA;
      float mB=hp.z*(1.f/1024.f);
      float rsB=rsqrtf(hp.w*(1.f/1024.f)-mB*mB+EPSF), nmB=-mB*rsB;
      PHX(0); PHX(1); PHX(2); PHX(3); PHX(4); PHX(5); PHX(6); PHX(7);
    } else {
      float sA=0.f,qA=0.f,sB=0.f,qB=0.f;
      #pragma unroll
      for (int c2=0;c2<8;++c2){
        f16x8 hA=__builtin_bit_cast(f16x8,pP[2*c2]);
        f16x8 hB=__builtin_bit_cast(f16x8,pP[2*c2+1]);
        #pragma unroll
        for (int j=0;j<8;++j){
          float fa=(float)hA[j], fb=(float)hB[j];
          sA+=fa; qA+=fa*fa; sB+=fb; qB+=fb*fb;
        }
      }
      sA+=__shfl_xor(sA,16); qA+=__shfl_xor(qA,16); sB+=__shfl_xor(sB,16); qB+=__shfl_xor(qB,16);
      sA+=__shfl_xor(sA,32); qA+=__shfl_xor(qA,32); sB+=__shfl_xor(sB,32); qB+=__shfl_xor(qB,32);
      if (lane<16){ f32x4 pk={sA,qA,sB,qB}; *(f32x4*)(RED0+((v*16+lane)<<4))=pk; }
      if (li==3){
        float sS=0.f,qS=0.f,sT=0.f,qT=0.f;
        #pragma unroll
        for (int c2=0;c2<8;++c2){
          f16x8 tA=__builtin_bit_cast(f16x8,pS[2*c2]);
          f16x8 tB=__builtin_bit_cast(f16x8,pS[2*c2+1]);
          #pragma unroll
          for (int j=0;j<8;++j){
            float fa=(float)tA[j], fb=(float)tB[j];
            sS+=fa; qS+=fa*fa; sT+=fb; qT+=fb*fb;
          }
        }
        sS+=__shfl_xor(sS,16); qS+=__shfl_xor(qS,16); sT+=__shfl_xor(sT,16); qT+=__shfl_xor(qT,16);
        sS+=__shfl_xor(sS,32); qS+=__shfl_xor(qS,32); sT+=__shfl_xor(sT,32); qT+=__shfl_xor(qT,32);
        if (lane<16){ f32x4 pk={sS,qS,sT,qT}; *(f32x4*)(RED1+((v*16+lane)<<4))=pk; }
      }
      BARS;
      f32x4 hp={0.f,0.f,0.f,0.f};
      #pragma unroll
      for (int vv=0;vv<4;++vv) hp += *(const f32x4*)(RED0+((vv*16+l15)<<4));
      float mAf=hp.x*(1.f/1024.f);
      float rsAf=rsqrtf(hp.y*(1.f/1024.f)-mAf*mAf+EPSF), nmAf=-mAf*rsAf;
      float mBf=hp.z*(1.f/1024.f);
      float rsBf=rsqrtf(hp.w*(1.f/1024.f)-mBf*mBf+EPSF), nmBf=-mBf*rsBf;
      const _Float16 hrA=(_Float16)rsAf, hmA=(_Float16)nmAf, hrB=(_Float16)rsBf, hmB=(_Float16)nmBf;
      const f16x8 rsA8={hrA,hrA,hrA,hrA,hrA,hrA,hrA,hrA};
      const f16x8 nmA8={hmA,hmA,hmA,hmA,hmA,hmA,hmA,hmA};
      const f16x8 rsB8={hrB,hrB,hrB,hrB,hrB,hrB,hrB,hrB};
      const f16x8 nmB8={hmB,hmB,hmB,hmB,hmB,hmB,hmB,hmB};
      if (li==3 && t>=1){
        f32x4 sp0={0.f,0.f,0.f,0.f}, sp1={0.f,0.f,0.f,0.f};
        #pragma unroll
        for (int vv=0;vv<4;++vv){
          sp0 += *(const f32x4*)(RED1+((vv*16+(r0&15))<<4));
          sp1 += *(const f32x4*)(RED1+((vv*16+(r1&15))<<4));
        }
        float gv=SGSB[col], bv=SGSB[16+col];
        float s0=(r0<16)? sp0.x : sp0.z, q0=(r0<16)? sp0.y : sp0.w;
        float m0=s0*(1.f/1024.f);
        float rs0=rsqrtf(q0*(1.f/1024.f)-m0*m0+EPSF);
        y[(size_t)(t-1)*BD_+(size_t)r0*D_+wr*16+col]=(pns.x-m0)*rs0*gv+bv;
        float s1v=(r1<16)? sp1.x : sp1.z, q1v=(r1<16)? sp1.y : sp1.w;
        float m1=s1v*(1.f/1024.f);
        float rs1=rsqrtf(q1v*(1.f/1024.f)-m1*m1+EPSF);
        y[(size_t)(t-1)*BD_+(size_t)r1*D_+wr*16+col]=(pns.y-m1)*rs1*gv+bv;
      }
      PHN(0); PHN(1); PHN(2); PHN(3); PHN(4); PHN(5); PHN(6); PHN(7);
    }

    *(f32x4*)(smem+LDS_DUMP + (((v*4+0)*64+lane)<<4)) = accF0;
    *(f32x4*)(smem+LDS_DUMP + (((v*4+1)*64+lane)<<4)) = accF1;
    *(f32x4*)(smem+LDS_DUMP + (((v*4+2)*64+lane)<<4)) = accC0;
    *(f32x4*)(smem+LDS_DUMP + (((v*4+3)*64+lane)<<4)) = accC1;
    BARS;

    {
      const int rtl = v>>1;
      const int lg20 = (v&1)*2, lg21 = (v&1)*2+1;
      float fF0=0.f,fF1=0.f,fC0=0.f,fC1=0.f;
      #pragma unroll
      for (int v2=0;v2<4;++v2){
        const char* db = smem+LDS_DUMP + v2*4096;
        fF0 += *(const float*)(db + (((0+rtl)*64 + lg20*16+col)<<4) + rp*4);
        fF1 += *(const float*)(db + (((0+rtl)*64 + lg21*16+col)<<4) + rp*4);
        fC0 += *(const float*)(db + (((2+rtl)*64 + lg20*16+col)<<4) + rp*4);
        fC1 += *(const float*)(db + (((2+rtl)*64 + lg21*16+col)<<4) + rp*4);
      }
      float bfc=BIAS[col], bcc=BIAS[16+col];
      float preF0=fminf(fmaxf(fF0+bfc,-30.f),30.f);
      float preC0=fminf(fmaxf(fC0+bcc,-30.f),30.f);
      float preF1=fminf(fmaxf(fF1+bfc,-30.f),30.f);
      float preC1=fminf(fmaxf(fC1+bcc,-30.f),30.f);
      float fg0=1.f/(1.f+__expf(-preF0)), e0=__expf(-2.f*preC0);
      float cd0=(1.f-e0)/(1.f+e0);
      float fg1=1.f/(1.f+__expf(-preF1)), e1=__expf(-2.f*preC1);
      float cd1=(1.f-e1)/(1.f+e1);
      float ns0=fg0*sreg.x+(1.f-fg0)*cd0;
      float ns1=fg1*sreg.y+(1.f-fg1)*cd1;
      sreg.x=ns0; sreg.y=ns1;
      if (li==3){ pns.x=ns0; pns.y=ns1; }
      NSf[r0*NSTR+col]=ns0;
      NSf[r1*NSTR+col]=ns1;
    }
    WAITL;   // same-wave NSf rows: intra-wave LDS order suffices

    if (lane<16){
      int row = v*8 + (lane>>1), hf = lane&1;
      const float* nr = NSf + row*NSTR + hf*8;
      f32x4 q0 = *(const f32x4*)nr, q1 = *(const f32x4*)(nr+4);
      unsigned w0=pk2h(q0[0],q0[1]), w1=pk2h(q0[2],q0[3]);
      unsigned w2=pk2h(q1[0],q1[1]), w3=pk2h(q1[2],q1[3]);
      unsigned short* sd = H16 + ((size_t)li*513 + (size_t)(t+1))*32768 + row*1024 + wr*16 + hf*8;
      cstore16(sd, w0, w1, w2, w3);
      if (t==T_-1){
        float* op = ostate + (size_t)li*BD_ + (size_t)row*D_ + wr*16 + hf*8;
        *(f32x4*)op = q0; *(f32x4*)(op+4) = q1;
      }
    }

    // ---- arrive: per-wave store drain, raw barrier, single bump to split counter
    DRAINV;
    BARS;
    if (tid==0)
      __hip_atomic_fetch_add(bumpc, 1u, __ATOMIC_RELAXED, __HIP_MEMORY_SCOPE_AGENT);

    // ---- prefetch h/x for t+1 (off the own-state critical path)
    if (t+1 < T_){
      if (li==0){
        u64 sbH=(u64)(uintptr_t)(x + (size_t)(t+1)*BD_);
        LOAD_X(sbH);
      } else {
        if (tid==0) poll8(upb, 8u*(unsigned)(t+2));
        BARS;
        u64 sbH=(u64)(uintptr_t)(H16 + ((size_t)(li-1)*513 + (size_t)(t+2))*32768);
        LOAD_H(sbH);
      }
    }
  }

  // ---- tail: y[511]
  if (li==3){
    if (tid==0) poll8(prog + (3*8)*16, 8u*(unsigned)T_);
    BARS;
    u64 sbS = (u64)(uintptr_t)(H16 + ((size_t)3*513 + (size_t)T_)*32768);
    LOAD_STATE(sbS);
    WAITV(0);
    float sS=0.f,qS=0.f,sT=0.f,qT=0.f;
    #pragma unroll
    for (int c2=0;c2<8;++c2){
      f16x8 tA=__builtin_bit_cast(f16x8,pS[2*c2]);
      f16x8 tB=__builtin_bit_cast(f16x8,pS[2*c2+1]);
      #pragma unroll
      for (int j=0;j<8;++j){
        float fa=(float)tA[j], fb=(float)tB[j];
        sS+=fa; qS+=fa*fa; sT+=fb; qT+=fb*fb;
      }
    }
    sS+=__shfl_xor(sS,16); qS+=__shfl_xor(qS,16); sT+=__shfl_xor(sT,16); qT+=__shfl_xor(qT,16);
    sS+=__shfl_xor(sS,32); qS+=__shfl_xor(qS,32); sT+=__shfl_xor(sT,32); qT+=__shfl_xor(qT,32);
    if (lane<16){ f32x4 pk={sS,qS,sT,qT}; *(f32x4*)(RED1+((v*16+lane)<<4))=pk; }
    BARS;
    f32x4 sp0={0.f,0.f,0.f,0.f}, sp1={0.f,0.f,0.f,0.f};
    #pragma unroll
    for (int vv=0;vv<4;++vv){
      sp0 += *(const f32x4*)(RED1+((vv*16+(r0&15))<<4));
      sp1 += *(const f32x4*)(RED1+((vv*16+(r1&15))<<4));
    }
    float gv=SGSB[col], bv=SGSB[16+col];
    float s0=(r0<16)? sp0.x : sp0.z, q0=(r0<16)? sp0.y : sp0.w;
    float m0=s0*(1.f/1024.f);
    float rs0=rsqrtf(q0*(1.f/1024.f)-m0*m0+EPSF);
    y[(size_t)(T_-1)*BD_+(size_t)r0*D_+wr*16+col]=(pns.x-m0)*rs0*gv+bv;
    float s1v=(r1<16)? sp1.x : sp1.z, q1v=(r1<16)? sp1.y : sp1.w;
    float m1=s1v*(1.f/1024.f);
    float rs1=rsqrtf(q1v*(1.f/1024.f)-m1*m1+EPSF);
    y[(size_t)(T_-1)*BD_+(size_t)r1*D_+wr*16+col]=(pns.y-m1)*rs1*gv+bv;
  }
}

extern "C" void kernel_launch(void* const* d_in, const int* in_sizes, int n_in,
                              void* d_out, int out_size, void* d_ws, size_t ws_size,
                              hipStream_t stream){
  (void)in_sizes; (void)n_in; (void)out_size; (void)ws_size;
  const float* x   = (const float*)d_in[0];
  const float* st0 = (const float*)d_in[1];
  const float* Wf  = (const float*)d_in[2];
  const float* Uf  = (const float*)d_in[3];
  const float* bfv = (const float*)d_in[4];
  const float* Wc  = (const float*)d_in[5];
  const float* Uc  = (const float*)d_in[6];
  const float* bcv = (const float*)d_in[7];
  const float* pg  = (const float*)d_in[8];
  const float* pb  = (const float*)d_in[9];
  const float* sg  = (const float*)d_in[10];
  const float* sbv = (const float*)d_in[11];

  float* y      = (float*)d_out;
  float* ostate = y + (size_t)T_*BD_;
  char* ws = (char*)d_ws;

  (void)hipMemsetAsync(ws, 0, 4096, stream);
  hipLaunchKernelGGL(crs_prepass, dim3(8192), dim3(256), 0, stream,
                     Wf, Uf, Wc, Uc, (unsigned short*)(ws+WSO_WT));
  hipLaunchKernelGGL(crs_prep2, dim3(L_), dim3(256), 0, stream,
                     st0, (unsigned short*)(ws+WSO_H16));
  (void)hipFuncSetAttribute((const void*)crs_main, hipFuncAttributeMaxDynamicSharedMemorySize, LDS_TOTAL);
  hipLaunchKernelGGL(crs_main, dim3(NWG), dim3(TPB), LDS_TOTAL, stream,
                     x, st0, bfv, bcv, pg, pb, sg, sbv, y, ostate,
                     (const unsigned short*)(ws+WSO_WT), ws);
}